// Round 1
// baseline (1125.055 us; speedup 1.0000x reference)
//
#include <hip/hip_runtime.h>
#include <hip/hip_bf16.h>
#include <stdint.h>

#define T_SEQ 4096
#define HIDDEN 2048
#define NQH 32
#define NKVH 8
#define DH 128
#define DVH 96
#define WWIN 512
#define QKVN 5888           // 32*128 + 8*128 + 8*96
#define KOFF 4096
#define VOFF 5120
#define ATTN 3072           // 32*96
#define QSCALE 0.08838834764831845f  // 128^-0.5

typedef uint16_t u16;
typedef uint32_t u32;
typedef __bf16 bfrag8 __attribute__((ext_vector_type(8)));
typedef float f32x4v __attribute__((ext_vector_type(4)));

__device__ __forceinline__ u16 f2bf(float x) {
  u32 u = __float_as_uint(x);
  return (u16)((u + 0x7fffu + ((u >> 16) & 1u)) >> 16);
}
__device__ __forceinline__ float bflo(u32 u) { return __uint_as_float(u << 16); }
__device__ __forceinline__ float bfhi(u32 u) { return __uint_as_float(u & 0xffff0000u); }
__device__ __forceinline__ float bf2f(u16 v) { return __uint_as_float(((u32)v) << 16); }

// ---------------- f32 -> bf16 bulk convert ----------------
__global__ void cvt_kernel(const float* __restrict__ in, u16* __restrict__ out, int n4) {
  int i = blockIdx.x * blockDim.x + threadIdx.x;
  int st = gridDim.x * blockDim.x;
  for (; i < n4; i += st) {
    float4 v = ((const float4*)in)[i];
    ushort4 o;
    o.x = f2bf(v.x); o.y = f2bf(v.y); o.z = f2bf(v.z); o.w = f2bf(v.w);
    ((ushort4*)out)[i] = o;
  }
}

// ---------------- bf16 NT GEMM: C[M][N] = A[M][K] * B[N][K]^T ----------------
// m97-style: 128x128 tile, BK=32, 4 waves (2x2), each wave 64x64 via 4x4 mfma_16x16x32
template<int OUT_F32>
__global__ __launch_bounds__(256) void gemm_nt(const u16* __restrict__ A,
                                               const u16* __restrict__ B,
                                               void* __restrict__ Cp,
                                               int M, int N, int K) {
  __shared__ u16 Asm[128 * 32];
  __shared__ u16 Bsm[128 * 32];
  const int tid = threadIdx.x;
  const int wv = tid >> 6, lane = tid & 63;
  const int bm = blockIdx.x * 128, bn = blockIdx.y * 128;
  const int wm = (wv >> 1) * 64, wn = (wv & 1) * 64;
  const int srow = lane >> 2;          // staging row within 16-row chunk
  const int scol = (lane & 3) * 8;     // staging k-offset (elements)
  const int fr = lane & 15, fk = (lane >> 4) * 8;
  f32x4v acc[4][4];
#pragma unroll
  for (int i = 0; i < 4; i++)
#pragma unroll
    for (int j = 0; j < 4; j++) acc[i][j] = {0.f, 0.f, 0.f, 0.f};

  for (int kt = 0; kt < K; kt += 32) {
    __syncthreads();
#pragma unroll
    for (int c = 0; c < 2; c++) {
      const int ci = wv * 2 + c;  // 0..7: 16-row chunk index
      const u16* ga = A + (size_t)(bm + ci * 16 + srow) * K + kt + scol;
      const u16* gb = B + (size_t)(bn + ci * 16 + srow) * K + kt + scol;
      __builtin_amdgcn_global_load_lds((const __attribute__((address_space(1))) u32*)ga,
                                       (__attribute__((address_space(3))) u32*)(Asm + ci * 512),
                                       16, 0, 0);
      __builtin_amdgcn_global_load_lds((const __attribute__((address_space(1))) u32*)gb,
                                       (__attribute__((address_space(3))) u32*)(Bsm + ci * 512),
                                       16, 0, 0);
    }
    __syncthreads();
    bfrag8 af[4], bf[4];
#pragma unroll
    for (int i = 0; i < 4; i++) af[i] = *(const bfrag8*)(Asm + (wm + i * 16 + fr) * 32 + fk);
#pragma unroll
    for (int j = 0; j < 4; j++) bf[j] = *(const bfrag8*)(Bsm + (wn + j * 16 + fr) * 32 + fk);
#pragma unroll
    for (int i = 0; i < 4; i++)
#pragma unroll
      for (int j = 0; j < 4; j++)
        acc[i][j] = __builtin_amdgcn_mfma_f32_16x16x32_bf16(af[i], bf[j], acc[i][j], 0, 0, 0);
  }
  const int orow = (lane >> 4) * 4, ocol = lane & 15;
#pragma unroll
  for (int i = 0; i < 4; i++)
#pragma unroll
    for (int j = 0; j < 4; j++) {
      size_t base = (size_t)(bm + wm + i * 16 + orow) * N + (size_t)(bn + wn + j * 16 + ocol);
#pragma unroll
      for (int r = 0; r < 4; r++) {
        if (OUT_F32) ((float*)Cp)[base + (size_t)r * N] = acc[i][j][r];
        else         ((u16*)Cp)[base + (size_t)r * N] = f2bf(acc[i][j][r]);
      }
    }
}

// ---------------- RoPE in-place on q,k (q also pre-scaled) ----------------
__global__ void rope_kernel(u16* __restrict__ qkv, const int* __restrict__ pos) {
  int gid = blockIdx.x * 256 + threadIdx.x;   // T * 40 * 64 threads
  int d = gid & 63;
  int r = gid >> 6;
  int hh = r % 40;
  int t = r / 40;
  if (t >= T_SEQ) return;
  int off = (hh < 32) ? hh * 128 : KOFF + (hh - 32) * 128;
  u16* p = qkv + (size_t)t * QKVN + off + d;
  float x1 = bf2f(p[0]);
  float x2 = bf2f(p[64]);
  // inv_freq = 1e6^(-d/64) = 2^(-d * log2(1e6)/64)
  float inv_freq = exp2f(-(float)d * 0.3114307588956852f);
  float ang = (float)pos[t] * inv_freq;
  float c = cosf(ang), s = sinf(ang);
  float y1 = x1 * c - x2 * s;
  float y2 = x2 * c + x1 * s;
  if (hh < 32) { y1 *= QSCALE; y2 *= QSCALE; }
  p[0] = f2bf(y1);
  p[64] = f2bf(y2);
}

// ---------------- sliding-window attention with sink (f32, round-1 simple) ----
// block: 16 queries x 1 q-head. thread (qi, s): key lane s, value dims s*6..s*6+5
__global__ __launch_bounds__(256) void attn_kernel(const u16* __restrict__ qkv,
                                                   const float* __restrict__ sink_bias,
                                                   u16* __restrict__ attn_out) {
  __shared__ u32 q_sm[16][68];  // 16 rows x 128 bf16 (64 u32), padded to 68 (16B-aligned rows)
  __shared__ u32 k_sm[16][68];
  __shared__ u32 v_sm[16][52];  // 16 rows x 96 bf16 (48 u32), padded to 52
  const int t0 = blockIdx.x * 16;
  const int h = blockIdx.y, hk = h >> 2;
  const int tid = threadIdx.x;
  const int qi = tid >> 4, s = tid & 15;
  const int lane = tid & 63;
  const int tq = t0 + qi;

  { // stage q tile (post-rope, pre-scaled)
    int rr = tid >> 4, m = tid & 15;
    const u16* g = qkv + (size_t)(t0 + rr) * QKVN + h * DH + m * 8;
    *(uint4*)&q_sm[rr][m * 4] = *(const uint4*)g;
  }

  float m_run = sink_bias[h];  // sink logit folded into softmax init: l=exp(sink-m)=1
  float l_run = 1.0f;
  float o0 = 0, o1 = 0, o2 = 0, o3 = 0, o4 = 0, o5 = 0;

  int cb0 = max(0, t0 - (WWIN - 1)) & ~15;
  for (int cb = cb0; cb < t0 + 16; cb += 16) {
    __syncthreads();
    { // stage K chunk rows cb..cb+15
      int rr = tid >> 4, m = tid & 15;
      const u16* g = qkv + (size_t)(cb + rr) * QKVN + KOFF + hk * DH + m * 8;
      *(uint4*)&k_sm[rr][m * 4] = *(const uint4*)g;
      if (tid < 192) {  // stage V chunk: 16 rows x 96 bf16
        int rv = tid / 12, mv = tid % 12;
        const u16* gv = qkv + (size_t)(cb + rv) * QKVN + VOFF + hk * DVH + mv * 8;
        *(uint4*)&v_sm[rv][mv * 4] = *(const uint4*)gv;
      }
    }
    __syncthreads();

    int tk = cb + s;
    bool valid = (tk <= tq) && (tk > tq - WWIN);
    float sc = -3.0e38f;
    if (valid) {
      const uint4* qr = (const uint4*)&q_sm[qi][0];
      const uint4* kr = (const uint4*)&k_sm[s][0];
      float a = 0.f;
#pragma unroll
      for (int p2 = 0; p2 < 16; p2++) {
        uint4 qa = qr[p2], kb = kr[p2];
        a = fmaf(bflo(qa.x), bflo(kb.x), a);
        a = fmaf(bfhi(qa.x), bfhi(kb.x), a);
        a = fmaf(bflo(qa.y), bflo(kb.y), a);
        a = fmaf(bfhi(qa.y), bfhi(kb.y), a);
        a = fmaf(bflo(qa.z), bflo(kb.z), a);
        a = fmaf(bfhi(qa.z), bfhi(kb.z), a);
        a = fmaf(bflo(qa.w), bflo(kb.w), a);
        a = fmaf(bfhi(qa.w), bfhi(kb.w), a);
      }
      sc = a;
    }
    // row (16-lane group) max
    float cm = sc;
    cm = fmaxf(cm, __shfl_xor(cm, 1));
    cm = fmaxf(cm, __shfl_xor(cm, 2));
    cm = fmaxf(cm, __shfl_xor(cm, 4));
    cm = fmaxf(cm, __shfl_xor(cm, 8));
    float m_new = fmaxf(m_run, cm);
    float pj = valid ? __expf(sc - m_new) : 0.f;
    float ls = pj;
    ls += __shfl_xor(ls, 1);
    ls += __shfl_xor(ls, 2);
    ls += __shfl_xor(ls, 4);
    ls += __shfl_xor(ls, 8);
    float corr = __expf(m_run - m_new);
    l_run = l_run * corr + ls;
    o0 *= corr; o1 *= corr; o2 *= corr; o3 *= corr; o4 *= corr; o5 *= corr;
    int base = lane & 48;
#pragma unroll
    for (int j = 0; j < 16; j++) {
      float pv = __shfl(pj, base + j);
      u32 va = v_sm[j][s * 3 + 0];
      u32 vb = v_sm[j][s * 3 + 1];
      u32 vc = v_sm[j][s * 3 + 2];
      o0 = fmaf(pv, bflo(va), o0);
      o1 = fmaf(pv, bfhi(va), o1);
      o2 = fmaf(pv, bflo(vb), o2);
      o3 = fmaf(pv, bfhi(vb), o3);
      o4 = fmaf(pv, bflo(vc), o4);
      o5 = fmaf(pv, bfhi(vc), o5);
    }
    m_run = m_new;
  }
  float inv = 1.0f / l_run;
  u16* op = attn_out + (size_t)tq * ATTN + h * DVH + s * 6;
  op[0] = f2bf(o0 * inv);
  op[1] = f2bf(o1 * inv);
  op[2] = f2bf(o2 * inv);
  op[3] = f2bf(o3 * inv);
  op[4] = f2bf(o4 * inv);
  op[5] = f2bf(o5 * inv);
}

// ---------------- launcher ----------------
extern "C" void kernel_launch(void* const* d_in, const int* in_sizes, int n_in,
                              void* d_out, int out_size, void* d_ws, size_t ws_size,
                              hipStream_t stream) {
  const int* positions = (const int*)d_in[0];
  const float* hidden = (const float*)d_in[1];
  const float* qkv_w = (const float*)d_in[2];
  const float* o_w = (const float*)d_in[3];
  const float* sink = (const float*)d_in[4];
  char* ws = (char*)d_ws;

  // workspace layout (attn_bf reuses the hs_bf/w1_bf region, dead after gemm1):
  u16* hs_bf   = (u16*)(ws + 0);          // 16,777,216 B
  u16* w1_bf   = (u16*)(ws + 16777216);   // 24,117,248 B
  u16* attn_bf = (u16*)(ws + 0);          // 25,165,824 B (overlaps hs/w1, written later)
  u16* w2_bf   = (u16*)(ws + 40894464);   // 12,582,912 B
  u16* qkv_bf  = (u16*)(ws + 53477376);   // 48,234,496 B  -> total 101,711,872 B

  cvt_kernel<<<dim3(1024), dim3(256), 0, stream>>>(hidden, hs_bf, 8388608 / 4);
  cvt_kernel<<<dim3(1024), dim3(256), 0, stream>>>(qkv_w, w1_bf, 12058624 / 4);
  cvt_kernel<<<dim3(1024), dim3(256), 0, stream>>>(o_w, w2_bf, 6291456 / 4);

  gemm_nt<0><<<dim3(32, 46), dim3(256), 0, stream>>>(hs_bf, w1_bf, (void*)qkv_bf,
                                                     T_SEQ, QKVN, HIDDEN);
  rope_kernel<<<dim3(40960), dim3(256), 0, stream>>>(qkv_bf, positions);
  attn_kernel<<<dim3(T_SEQ / 16, NQH), dim3(256), 0, stream>>>(qkv_bf, sink, attn_bf);
  gemm_nt<1><<<dim3(32, 16), dim3(256), 0, stream>>>(attn_bf, w2_bf, d_out,
                                                     T_SEQ, HIDDEN, ATTN);
}

// Round 2
// 348.999 us; speedup vs baseline: 3.2237x; 3.2237x over previous
//
#include <hip/hip_runtime.h>
#include <hip/hip_bf16.h>
#include <stdint.h>

#define T_SEQ 4096
#define HIDDEN 2048
#define NQH 32
#define NKVH 8
#define DH 128
#define DVH 96
#define WWIN 512
#define QKVN 5888           // 32*128 + 8*128 + 8*96
#define KOFF 4096
#define VOFF 5120
#define ATTN 3072           // 32*96
#define QSCALE 0.08838834764831845f  // 128^-0.5

typedef uint16_t u16;
typedef uint32_t u32;
typedef __bf16 bfrag8 __attribute__((ext_vector_type(8)));
typedef float f32x4v __attribute__((ext_vector_type(4)));

__device__ __forceinline__ u16 f2bf(float x) {
  u32 u = __float_as_uint(x);
  return (u16)((u + 0x7fffu + ((u >> 16) & 1u)) >> 16);
}
__device__ __forceinline__ float bf2f(u16 v) { return __uint_as_float(((u32)v) << 16); }

// ---------------- f32 -> bf16 bulk convert ----------------
__global__ void cvt_kernel(const float* __restrict__ in, u16* __restrict__ out, int n4) {
  int i = blockIdx.x * blockDim.x + threadIdx.x;
  int st = gridDim.x * blockDim.x;
  for (; i < n4; i += st) {
    float4 v = ((const float4*)in)[i];
    ushort4 o;
    o.x = f2bf(v.x); o.y = f2bf(v.y); o.z = f2bf(v.z); o.w = f2bf(v.w);
    ((ushort4*)out)[i] = o;
  }
}

// ---------------- bf16 NT GEMM: C[M][N] = A[M][K] * B[N][K]^T ----------------
template<int OUT_F32>
__global__ __launch_bounds__(256) void gemm_nt(const u16* __restrict__ A,
                                               const u16* __restrict__ B,
                                               void* __restrict__ Cp,
                                               int M, int N, int K) {
  __shared__ u16 Asm[128 * 32];
  __shared__ u16 Bsm[128 * 32];
  const int tid = threadIdx.x;
  const int wv = tid >> 6, lane = tid & 63;
  const int bm = blockIdx.x * 128, bn = blockIdx.y * 128;
  const int wm = (wv >> 1) * 64, wn = (wv & 1) * 64;
  const int srow = lane >> 2;
  const int scol = (lane & 3) * 8;
  const int fr = lane & 15, fk = (lane >> 4) * 8;
  f32x4v acc[4][4];
#pragma unroll
  for (int i = 0; i < 4; i++)
#pragma unroll
    for (int j = 0; j < 4; j++) acc[i][j] = {0.f, 0.f, 0.f, 0.f};

  for (int kt = 0; kt < K; kt += 32) {
    __syncthreads();
#pragma unroll
    for (int c = 0; c < 2; c++) {
      const int ci = wv * 2 + c;
      const u16* ga = A + (size_t)(bm + ci * 16 + srow) * K + kt + scol;
      const u16* gb = B + (size_t)(bn + ci * 16 + srow) * K + kt + scol;
      __builtin_amdgcn_global_load_lds((const __attribute__((address_space(1))) u32*)ga,
                                       (__attribute__((address_space(3))) u32*)(Asm + ci * 512),
                                       16, 0, 0);
      __builtin_amdgcn_global_load_lds((const __attribute__((address_space(1))) u32*)gb,
                                       (__attribute__((address_space(3))) u32*)(Bsm + ci * 512),
                                       16, 0, 0);
    }
    __syncthreads();
    bfrag8 af[4], bf[4];
#pragma unroll
    for (int i = 0; i < 4; i++) af[i] = *(const bfrag8*)(Asm + (wm + i * 16 + fr) * 32 + fk);
#pragma unroll
    for (int j = 0; j < 4; j++) bf[j] = *(const bfrag8*)(Bsm + (wn + j * 16 + fr) * 32 + fk);
#pragma unroll
    for (int i = 0; i < 4; i++)
#pragma unroll
      for (int j = 0; j < 4; j++)
        acc[i][j] = __builtin_amdgcn_mfma_f32_16x16x32_bf16(af[i], bf[j], acc[i][j], 0, 0, 0);
  }
  const int orow = (lane >> 4) * 4, ocol = lane & 15;
#pragma unroll
  for (int i = 0; i < 4; i++)
#pragma unroll
    for (int j = 0; j < 4; j++) {
      size_t base = (size_t)(bm + wm + i * 16 + orow) * N + (size_t)(bn + wn + j * 16 + ocol);
#pragma unroll
      for (int r = 0; r < 4; r++) {
        if (OUT_F32) ((float*)Cp)[base + (size_t)r * N] = acc[i][j][r];
        else         ((u16*)Cp)[base + (size_t)r * N] = f2bf(acc[i][j][r]);
      }
    }
}

// ---------------- RoPE in-place on q,k (q also pre-scaled) ----------------
__global__ void rope_kernel(u16* __restrict__ qkv, const int* __restrict__ pos) {
  int gid = blockIdx.x * 256 + threadIdx.x;
  int d = gid & 63;
  int r = gid >> 6;
  int hh = r % 40;
  int t = r / 40;
  if (t >= T_SEQ) return;
  int off = (hh < 32) ? hh * 128 : KOFF + (hh - 32) * 128;
  u16* p = qkv + (size_t)t * QKVN + off + d;
  float x1 = bf2f(p[0]);
  float x2 = bf2f(p[64]);
  float inv_freq = exp2f(-(float)d * 0.3114307588956852f);
  float ang = (float)pos[t] * inv_freq;
  float c = cosf(ang), s = sinf(ang);
  float y1 = x1 * c - x2 * s;
  float y2 = x2 * c + x1 * s;
  if (hh < 32) { y1 *= QSCALE; y2 *= QSCALE; }
  p[0] = f2bf(y1);
  p[64] = f2bf(y2);
}

// ---------------- V transpose: qkv V region -> vt[hk][dv][t] ----------------
__global__ __launch_bounds__(256) void vt_kernel(const u16* __restrict__ qkv,
                                                 u16* __restrict__ vt) {
  __shared__ u16 tile[64][100];  // stride 100 u16 = 200 B (8B aligned)
  const int t0 = blockIdx.x * 64;
  const int hk = blockIdx.y;
  const int tid = threadIdx.x;
#pragma unroll
  for (int i = 0; i < 3; i++) {
    int idx = i * 256 + tid;          // 0..767 : 64 rows x 12 chunks of 8
    int row = idx / 12, ch = idx % 12;
    const u16* g = qkv + (size_t)(t0 + row) * QKVN + VOFF + hk * DVH + ch * 8;
    uint2 a = *(const uint2*)g;
    uint2 b = *(const uint2*)(g + 4);
    *(uint2*)&tile[row][ch * 8] = a;
    *(uint2*)&tile[row][ch * 8 + 4] = b;
  }
  __syncthreads();
#pragma unroll
  for (int i = 0; i < 3; i++) {
    int idx = i * 256 + tid;          // 0..767 : 96 dv x 8 t-chunks of 8
    int dv = idx >> 3, tc = (idx & 7) * 8;
    union { uint4 v4; u16 s[8]; } o;
#pragma unroll
    for (int j = 0; j < 8; j++) o.s[j] = tile[tc + j][dv];
    *(uint4*)(vt + (((size_t)(hk * 96 + dv)) << 12) + t0 + tc) = o.v4;
  }
}

// ---------------- MFMA sliding-window attention with sink ----------------
// block: 1 KV head x 32 q-positions, 4 waves; wave w = q-head hk*4+w
__global__ __launch_bounds__(256, 2) void attn_mfma(const u16* __restrict__ qkv,
                                                    const u16* __restrict__ vt,
                                                    const float* __restrict__ sink_bias,
                                                    u16* __restrict__ attn_out) {
  __shared__ u16 k_lds[64 * 128];   // swizzled row-major [key][d], 16 KB
  __shared__ u16 v_lds[96 * 64];    // swizzled row-major [dv][key] (V^T), 12 KB
  __shared__ u16 p_lds[4][2048];    // per-wave P in A-frag subtile layout, 16 KB

  const int tid = threadIdx.x;
  const int wv = tid >> 6;
  const int lane = tid & 63;
  const int g = lane >> 4;
  const int c = lane & 15;
  const int t0 = blockIdx.x * 32;
  const int hk = blockIdx.y;
  const int h = hk * 4 + wv;

  // Q A-fragments: 2 mfrags x 4 kfrags; row = c, d = kf*32 + g*8 (post-rope, pre-scaled)
  bfrag8 qf[2][4];
#pragma unroll
  for (int m = 0; m < 2; m++)
#pragma unroll
    for (int kf = 0; kf < 4; kf++)
      qf[m][kf] = *(const bfrag8*)(qkv + (size_t)(t0 + m * 16 + c) * QKVN + h * DH + kf * 32 + g * 8);

  f32x4v acc_o[2][6];
#pragma unroll
  for (int m = 0; m < 2; m++)
#pragma unroll
    for (int n = 0; n < 6; n++) acc_o[m][n] = {0.f, 0.f, 0.f, 0.f};

  const float sb = sink_bias[h];
  float m_run[2][4], l_run[2][4];
#pragma unroll
  for (int m = 0; m < 2; m++)
#pragma unroll
    for (int r = 0; r < 4; r++) { m_run[m][r] = sb; l_run[m][r] = 1.0f; }

  int cb0 = t0 - (WWIN - 1);
  cb0 = (cb0 < 0) ? 0 : (cb0 & ~63);

  for (int cb = cb0; cb < t0 + 32; cb += 64) {
    __syncthreads();
    // stage K tile (64 x 128, pre-swizzled source -> linear LDS dest)
#pragma unroll
    for (int it = 0; it < 4; it++) {
      int dest = it * 4096 + tid * 16;
      int row = dest >> 8;
      int src = dest ^ ((row & 7) << 4);
      const u16* gp = qkv + (size_t)(cb + row) * QKVN + KOFF + hk * DH + ((src & 255) >> 1);
      __builtin_amdgcn_global_load_lds((const __attribute__((address_space(1))) u32*)gp,
                                       (__attribute__((address_space(3))) u32*)((char*)k_lds + dest),
                                       16, 0, 0);
    }
    // stage V^T tile (96 x 64, pre-swizzled source)
#pragma unroll
    for (int it = 0; it < 3; it++) {
      int dest = it * 4096 + tid * 16;
      int row = dest >> 7;
      int src = dest ^ ((row & 7) << 4);
      const u16* gp = vt + (((size_t)(hk * 96 + row)) << 12) + cb + ((src & 127) >> 1);
      __builtin_amdgcn_global_load_lds((const __attribute__((address_space(1))) u32*)gp,
                                       (__attribute__((address_space(3))) u32*)((char*)v_lds + dest),
                                       16, 0, 0);
    }
    __syncthreads();

    // S = Q K^T  (2 mfrags x 4 nfrags)
    f32x4v s[2][4];
#pragma unroll
    for (int m = 0; m < 2; m++)
#pragma unroll
      for (int n = 0; n < 4; n++) s[m][n] = {0.f, 0.f, 0.f, 0.f};
#pragma unroll
    for (int kf = 0; kf < 4; kf++) {
      bfrag8 kb[4];
#pragma unroll
      for (int n = 0; n < 4; n++) {
        int key = n * 16 + c;
        int byt = ((key << 8) + (kf << 6) + (g << 4)) ^ ((key & 7) << 4);
        kb[n] = *(const bfrag8*)((const char*)k_lds + byt);
      }
#pragma unroll
      for (int m = 0; m < 2; m++)
#pragma unroll
        for (int n = 0; n < 4; n++)
          s[m][n] = __builtin_amdgcn_mfma_f32_16x16x32_bf16(qf[m][kf], kb[n], s[m][n], 0, 0, 0);
    }

    // mask (wave-uniform branch; only edge chunks)
    if ((cb + 63 > t0) || (cb + WWIN < t0 + 32)) {
#pragma unroll
      for (int m = 0; m < 2; m++)
#pragma unroll
        for (int n = 0; n < 4; n++)
#pragma unroll
          for (int r = 0; r < 4; r++) {
            int rel = (t0 + m * 16 + g * 4 + r) - (cb + n * 16 + c);
            if (!(rel >= 0 && rel < WWIN)) s[m][n][r] = -3.0e38f;
          }
    }

    // online softmax (rows live in 16 col-lanes; reduce over 4 nfrags + 4 shfl)
    float corr[2][4];
#pragma unroll
    for (int m = 0; m < 2; m++)
#pragma unroll
      for (int r = 0; r < 4; r++) {
        float v0 = fmaxf(fmaxf(s[m][0][r], s[m][1][r]), fmaxf(s[m][2][r], s[m][3][r]));
        v0 = fmaxf(v0, __shfl_xor(v0, 1));
        v0 = fmaxf(v0, __shfl_xor(v0, 2));
        v0 = fmaxf(v0, __shfl_xor(v0, 4));
        v0 = fmaxf(v0, __shfl_xor(v0, 8));
        float mn = fmaxf(m_run[m][r], v0);
        corr[m][r] = __expf(m_run[m][r] - mn);
        m_run[m][r] = mn;
        float p0 = __expf(s[m][0][r] - mn);
        float p1 = __expf(s[m][1][r] - mn);
        float p2 = __expf(s[m][2][r] - mn);
        float p3 = __expf(s[m][3][r] - mn);
        s[m][0][r] = p0; s[m][1][r] = p1; s[m][2][r] = p2; s[m][3][r] = p3;
        float rs = p0 + p1 + p2 + p3;
        rs += __shfl_xor(rs, 1);
        rs += __shfl_xor(rs, 2);
        rs += __shfl_xor(rs, 4);
        rs += __shfl_xor(rs, 8);
        l_run[m][r] = l_run[m][r] * corr[m][r] + rs;
      }
#pragma unroll
    for (int m = 0; m < 2; m++)
#pragma unroll
      for (int n = 0; n < 6; n++)
#pragma unroll
      for (int r = 0; r < 4; r++) acc_o[m][n][r] *= corr[m][r];

    // write P (bf16) into per-wave A-frag subtile layout: packed 4 rows -> b64
#pragma unroll
    for (int m = 0; m < 2; m++)
#pragma unroll
      for (int n = 0; n < 4; n++) {
        u32 lo = (u32)f2bf(s[m][n][0]) | ((u32)f2bf(s[m][n][1]) << 16);
        u32 hi = (u32)f2bf(s[m][n][2]) | ((u32)f2bf(s[m][n][3]) << 16);
        int byt = ((m * 2 + (n >> 1)) << 10) | (g << 3) | ((c & 3) << 5) |
                  (((c >> 2) & 1) << 9) | ((((n & 1) * 2) + (c >> 3)) << 7);
        uint2 u; u.x = lo; u.y = hi;
        *(uint2*)((char*)&p_lds[wv][0] + byt) = u;
      }

    // O += P V  (per ksub: read P A-frags + V^T B-frags, 2x6 mfma)
#pragma unroll
    for (int ks = 0; ks < 2; ks++) {
      bfrag8 pa[2];
#pragma unroll
      for (int m = 0; m < 2; m++) {
        union { bfrag8 v; u16 s16[8]; } u;
#pragma unroll
        for (int j = 0; j < 4; j++) {
          int e = ((m * 2 + ks) << 9) + c + j * 16 + g * 64;
          u.s16[j] = p_lds[wv][e];
          u.s16[4 + j] = p_lds[wv][e + 256];
        }
        pa[m] = u.v;
      }
#pragma unroll
      for (int n = 0; n < 6; n++) {
        int dv = n * 16 + c;
        int byt = ((dv << 7) + (ks << 6) + (g << 4)) ^ ((dv & 7) << 4);
        bfrag8 vb = *(const bfrag8*)((const char*)v_lds + byt);
#pragma unroll
        for (int m = 0; m < 2; m++)
          acc_o[m][n] = __builtin_amdgcn_mfma_f32_16x16x32_bf16(pa[m], vb, acc_o[m][n], 0, 0, 0);
      }
    }
  }

  // epilogue: normalize and store
#pragma unroll
  for (int m = 0; m < 2; m++) {
    float inv[4];
#pragma unroll
    for (int r = 0; r < 4; r++) inv[r] = 1.0f / l_run[m][r];
#pragma unroll
    for (int n = 0; n < 6; n++)
#pragma unroll
      for (int r = 0; r < 4; r++) {
        int tq = t0 + m * 16 + g * 4 + r;
        attn_out[(size_t)tq * ATTN + h * DVH + n * 16 + c] = f2bf(acc_o[m][n][r] * inv[r]);
      }
  }
}

// ---------------- launcher ----------------
extern "C" void kernel_launch(void* const* d_in, const int* in_sizes, int n_in,
                              void* d_out, int out_size, void* d_ws, size_t ws_size,
                              hipStream_t stream) {
  const int* positions = (const int*)d_in[0];
  const float* hidden = (const float*)d_in[1];
  const float* qkv_w = (const float*)d_in[2];
  const float* o_w = (const float*)d_in[3];
  const float* sink = (const float*)d_in[4];
  char* ws = (char*)d_ws;

  // workspace layout:
  u16* hs_bf   = (u16*)(ws + 0);          // 16,777,216 B (dead after gemm1)
  u16* w1_bf   = (u16*)(ws + 16777216);   // 24,117,248 B (dead after gemm1)
  u16* attn_bf = (u16*)(ws + 0);          // 25,165,824 B (overlaps hs/w1)
  u16* vt_buf  = (u16*)(ws + 25165824);   //  6,291,456 B
  u16* w2_bf   = (u16*)(ws + 40894464);   // 12,582,912 B
  u16* qkv_bf  = (u16*)(ws + 53477376);   // 48,234,496 B

  cvt_kernel<<<dim3(1024), dim3(256), 0, stream>>>(hidden, hs_bf, 8388608 / 4);
  cvt_kernel<<<dim3(1024), dim3(256), 0, stream>>>(qkv_w, w1_bf, 12058624 / 4);
  cvt_kernel<<<dim3(1024), dim3(256), 0, stream>>>(o_w, w2_bf, 6291456 / 4);

  gemm_nt<0><<<dim3(32, 46), dim3(256), 0, stream>>>(hs_bf, w1_bf, (void*)qkv_bf,
                                                     T_SEQ, QKVN, HIDDEN);
  rope_kernel<<<dim3(40960), dim3(256), 0, stream>>>(qkv_bf, positions);
  vt_kernel<<<dim3(T_SEQ / 64, NKVH), dim3(256), 0, stream>>>(qkv_bf, vt_buf);
  attn_mfma<<<dim3(T_SEQ / 32, NKVH), dim3(256), 0, stream>>>(qkv_bf, vt_buf, sink, attn_bf);
  gemm_nt<1><<<dim3(32, 16), dim3(256), 0, stream>>>(attn_bf, w2_bf, d_out,
                                                     T_SEQ, HIDDEN, ATTN);
}

// Round 3
// 322.796 us; speedup vs baseline: 3.4853x; 1.0812x over previous
//
#include <hip/hip_runtime.h>
#include <hip/hip_bf16.h>
#include <stdint.h>

#define T_SEQ 4096
#define HIDDEN 2048
#define NQH 32
#define NKVH 8
#define DH 128
#define DVH 96
#define WWIN 512
#define QKVN 5888           // 32*128 + 8*128 + 8*96
#define KOFF 4096
#define VOFF 5120
#define ATTN 3072           // 32*96
#define QSCALE 0.08838834764831845f  // 128^-0.5

typedef uint16_t u16;
typedef uint32_t u32;
typedef __bf16 bfrag8 __attribute__((ext_vector_type(8)));
typedef float f32x4v __attribute__((ext_vector_type(4)));

__device__ __forceinline__ u16 f2bf(float x) {
  u32 u = __float_as_uint(x);
  return (u16)((u + 0x7fffu + ((u >> 16) & 1u)) >> 16);
}
__device__ __forceinline__ float bf2f(u16 v) { return __uint_as_float(((u32)v) << 16); }

// ---------------- f32 -> bf16 bulk convert ----------------
__global__ void cvt_kernel(const float* __restrict__ in, u16* __restrict__ out, int n4) {
  int i = blockIdx.x * blockDim.x + threadIdx.x;
  int st = gridDim.x * blockDim.x;
  for (; i < n4; i += st) {
    float4 v = ((const float4*)in)[i];
    ushort4 o;
    o.x = f2bf(v.x); o.y = f2bf(v.y); o.z = f2bf(v.z); o.w = f2bf(v.w);
    ((ushort4*)out)[i] = o;
  }
}

// =======================================================================
// Pipelined bf16 NT GEMM: C[M][N] = A[M][K] * B[N][K]^T
// BM=256, BN=WN*64, BK=32; 8 waves (WMxWN grid); 3 LDS buffers;
// counted vmcnt (never 0 in steady state), raw s_barrier (no vmcnt drain),
// setprio around MFMA clusters, XCD-bijective block swizzle.
// LDS packed layout: storage row = 2 M-rows (128B), XOR-swizzled
// byte ^= ((srow&7)<<4); staging pre-applies inverse on global source.
// =======================================================================
template<int WN, int OUT_F32>
__global__ __launch_bounds__(512, 2) void gemm_pipe(const u16* __restrict__ A,
                                                    const u16* __restrict__ B,
                                                    void* __restrict__ Cp,
                                                    int M, int N, int K, int nbm) {
  constexpr int BN = WN * 64;
  constexpr int WM = 8 / WN;           // 2 (WN=4) or 4 (WN=2)
  constexpr int MF = 16 / WM;          // m-frags per wave: 8 or 4
  constexpr int ASZ = 8192;            // u16 elements (16 KB)
  constexpr int BSZ = BN * 32;         // 8192 or 4096 u16
  constexpr int BUFSZ = ASZ + BSZ;
  constexpr int AIN = 2;               // gload instrs per wave for A tile
  constexpr int BIN = (WN == 4) ? 2 : 1;
  constexpr int LPT = AIN + BIN;       // loads per tile per wave

  extern __shared__ u16 lds[];

  const int tid = threadIdx.x;
  const int w = tid >> 6, lane = tid & 63;
  const int wr = w / WN, wc = w % WN;
  const int fr = lane & 15, kg = lane >> 4;

  const int nwg = gridDim.x;
  int bid = (int)blockIdx.x;
  if ((nwg & 7) == 0) bid = (bid & 7) * (nwg >> 3) + (bid >> 3);
  const int bm = (bid % nbm) * 256;
  const int bn = (bid / nbm) * BN;

  const int NT = K >> 5;

  f32x4v acc[MF][4];
#pragma unroll
  for (int m = 0; m < MF; m++)
#pragma unroll
    for (int n = 0; n < 4; n++) acc[m][n] = {0.f, 0.f, 0.f, 0.f};

  // ---- staging: dest byte D holds logical L = D ^ ((srow&7)<<4);
  // logical packed layout: L = srow*128 + c*2, element = T[2*srow + (c>>5)][c&31]
  auto stageA = [&](int t) {
    u16* dst = lds + (t % 3) * BUFSZ;
#pragma unroll
    for (int i = 0; i < AIN; i++) {
      int D = (w * AIN + i) * 1024 + lane * 16;
      int srow = D >> 7;
      int Dx = D ^ ((srow & 7) << 4);
      int c = (Dx >> 1) & 63;
      int m = 2 * srow + (c >> 5);
      int k = c & 31;
      const u16* src = A + (size_t)(bm + m) * K + (t << 5) + k;
      __builtin_amdgcn_global_load_lds((const __attribute__((address_space(1))) u32*)src,
                                       (__attribute__((address_space(3))) u32*)((char*)dst + D),
                                       16, 0, 0);
    }
  };
  auto stageB = [&](int t) {
    u16* dst = lds + (t % 3) * BUFSZ + ASZ;
#pragma unroll
    for (int i = 0; i < BIN; i++) {
      int D = (w * BIN + i) * 1024 + lane * 16;
      int srow = D >> 7;
      int Dx = D ^ ((srow & 7) << 4);
      int c = (Dx >> 1) & 63;
      int m = 2 * srow + (c >> 5);
      int k = c & 31;
      const u16* src = B + (size_t)(bn + m) * K + (t << 5) + k;
      __builtin_amdgcn_global_load_lds((const __attribute__((address_space(1))) u32*)src,
                                       (__attribute__((address_space(3))) u32*)((char*)dst + D),
                                       16, 0, 0);
    }
  };

  // prologue: tiles 0 and 1 in flight
  stageA(0); stageB(0);
  stageA(1); stageB(1);

  for (int t = 0; t < NT; ++t) {
    const u16* At = lds + (t % 3) * BUFSZ;
    const u16* Bt = At + ASZ;
    // wait tile t landed (per-wave); tile t+1's LPT loads stay in flight
    if (t + 1 < NT) asm volatile("s_waitcnt vmcnt(%0)" :: "n"(LPT));
    else            asm volatile("s_waitcnt vmcnt(0)");
    asm volatile("s_barrier" ::: "memory");

    // ---- phase 0: B-frags (once per tile) + first MF/2 A-frags
    bfrag8 bfr[4];
#pragma unroll
    for (int n = 0; n < 4; n++) {
      int nr = wc * 64 + n * 16 + fr;
      int byt = (((nr >> 1) << 7) + ((nr & 1) << 6) + (kg << 4)) ^ (((nr >> 1) & 7) << 4);
      bfr[n] = *(const bfrag8*)((const char*)Bt + byt);
    }
    bfrag8 afr[MF / 2];
#pragma unroll
    for (int m = 0; m < MF / 2; m++) {
      int mr = wr * (MF * 16) + m * 16 + fr;
      int byt = (((mr >> 1) << 7) + ((mr & 1) << 6) + (kg << 4)) ^ (((mr >> 1) & 7) << 4);
      afr[m] = *(const bfrag8*)((const char*)At + byt);
    }
    if (t + 2 < NT) stageA(t + 2);
    __builtin_amdgcn_s_setprio(1);
#pragma unroll
    for (int m = 0; m < MF / 2; m++)
#pragma unroll
      for (int n = 0; n < 4; n++)
        acc[m][n] = __builtin_amdgcn_mfma_f32_16x16x32_bf16(afr[m], bfr[n], acc[m][n], 0, 0, 0);
    __builtin_amdgcn_s_setprio(0);
    asm volatile("s_barrier" ::: "memory");

    // ---- phase 1: second MF/2 A-frags
    bfrag8 afr2[MF / 2];
#pragma unroll
    for (int m = 0; m < MF / 2; m++) {
      int mr = wr * (MF * 16) + (m + MF / 2) * 16 + fr;
      int byt = (((mr >> 1) << 7) + ((mr & 1) << 6) + (kg << 4)) ^ (((mr >> 1) & 7) << 4);
      afr2[m] = *(const bfrag8*)((const char*)At + byt);
    }
    if (t + 2 < NT) stageB(t + 2);
    __builtin_amdgcn_s_setprio(1);
#pragma unroll
    for (int m = 0; m < MF / 2; m++)
#pragma unroll
      for (int n = 0; n < 4; n++)
        acc[m + MF / 2][n] = __builtin_amdgcn_mfma_f32_16x16x32_bf16(afr2[m], bfr[n], acc[m + MF / 2][n], 0, 0, 0);
    __builtin_amdgcn_s_setprio(0);
  }

  // ---- epilogue: C-write (C layout: row = kg*4+r, col = fr per 16x16 frag)
  const int rb = bm + wr * (MF * 16);
  const int cb = bn + wc * 64;
#pragma unroll
  for (int m = 0; m < MF; m++)
#pragma unroll
    for (int n = 0; n < 4; n++) {
      size_t base = (size_t)(rb + m * 16 + kg * 4) * N + cb + n * 16 + fr;
#pragma unroll
      for (int r = 0; r < 4; r++) {
        if (OUT_F32) ((float*)Cp)[base + (size_t)r * N] = acc[m][n][r];
        else         ((u16*)Cp)[base + (size_t)r * N] = f2bf(acc[m][n][r]);
      }
    }
}

// ---------------- fallback bf16 NT GEMM (round-2 proven) ----------------
template<int OUT_F32>
__global__ __launch_bounds__(256) void gemm_nt(const u16* __restrict__ A,
                                               const u16* __restrict__ B,
                                               void* __restrict__ Cp,
                                               int M, int N, int K) {
  __shared__ u16 Asm[128 * 32];
  __shared__ u16 Bsm[128 * 32];
  const int tid = threadIdx.x;
  const int wv = tid >> 6, lane = tid & 63;
  const int bm = blockIdx.x * 128, bn = blockIdx.y * 128;
  const int wm = (wv >> 1) * 64, wn = (wv & 1) * 64;
  const int srow = lane >> 2;
  const int scol = (lane & 3) * 8;
  const int fr = lane & 15, fk = (lane >> 4) * 8;
  f32x4v acc[4][4];
#pragma unroll
  for (int i = 0; i < 4; i++)
#pragma unroll
    for (int j = 0; j < 4; j++) acc[i][j] = {0.f, 0.f, 0.f, 0.f};

  for (int kt = 0; kt < K; kt += 32) {
    __syncthreads();
#pragma unroll
    for (int c = 0; c < 2; c++) {
      const int ci = wv * 2 + c;
      const u16* ga = A + (size_t)(bm + ci * 16 + srow) * K + kt + scol;
      const u16* gb = B + (size_t)(bn + ci * 16 + srow) * K + kt + scol;
      __builtin_amdgcn_global_load_lds((const __attribute__((address_space(1))) u32*)ga,
                                       (__attribute__((address_space(3))) u32*)(Asm + ci * 512),
                                       16, 0, 0);
      __builtin_amdgcn_global_load_lds((const __attribute__((address_space(1))) u32*)gb,
                                       (__attribute__((address_space(3))) u32*)(Bsm + ci * 512),
                                       16, 0, 0);
    }
    __syncthreads();
    bfrag8 af[4], bf[4];
#pragma unroll
    for (int i = 0; i < 4; i++) af[i] = *(const bfrag8*)(Asm + (wm + i * 16 + fr) * 32 + fk);
#pragma unroll
    for (int j = 0; j < 4; j++) bf[j] = *(const bfrag8*)(Bsm + (wn + j * 16 + fr) * 32 + fk);
#pragma unroll
    for (int i = 0; i < 4; i++)
#pragma unroll
      for (int j = 0; j < 4; j++)
        acc[i][j] = __builtin_amdgcn_mfma_f32_16x16x32_bf16(af[i], bf[j], acc[i][j], 0, 0, 0);
  }
  const int orow = (lane >> 4) * 4, ocol = lane & 15;
#pragma unroll
  for (int i = 0; i < 4; i++)
#pragma unroll
    for (int j = 0; j < 4; j++) {
      size_t base = (size_t)(bm + wm + i * 16 + orow) * N + (size_t)(bn + wn + j * 16 + ocol);
#pragma unroll
      for (int r = 0; r < 4; r++) {
        if (OUT_F32) ((float*)Cp)[base + (size_t)r * N] = acc[i][j][r];
        else         ((u16*)Cp)[base + (size_t)r * N] = f2bf(acc[i][j][r]);
      }
    }
}

// ---------------- RoPE in-place on q,k (q also pre-scaled) ----------------
__global__ void rope_kernel(u16* __restrict__ qkv, const int* __restrict__ pos) {
  int gid = blockIdx.x * 256 + threadIdx.x;
  int d = gid & 63;
  int r = gid >> 6;
  int hh = r % 40;
  int t = r / 40;
  if (t >= T_SEQ) return;
  int off = (hh < 32) ? hh * 128 : KOFF + (hh - 32) * 128;
  u16* p = qkv + (size_t)t * QKVN + off + d;
  float x1 = bf2f(p[0]);
  float x2 = bf2f(p[64]);
  float inv_freq = exp2f(-(float)d * 0.3114307588956852f);
  float ang = (float)pos[t] * inv_freq;
  float c = cosf(ang), s = sinf(ang);
  float y1 = x1 * c - x2 * s;
  float y2 = x2 * c + x1 * s;
  if (hh < 32) { y1 *= QSCALE; y2 *= QSCALE; }
  p[0] = f2bf(y1);
  p[64] = f2bf(y2);
}

// ---------------- V transpose: qkv V region -> vt[hk][dv][t] ----------------
__global__ __launch_bounds__(256) void vt_kernel(const u16* __restrict__ qkv,
                                                 u16* __restrict__ vt) {
  __shared__ u16 tile[64][100];
  const int t0 = blockIdx.x * 64;
  const int hk = blockIdx.y;
  const int tid = threadIdx.x;
#pragma unroll
  for (int i = 0; i < 3; i++) {
    int idx = i * 256 + tid;
    int row = idx / 12, ch = idx % 12;
    const u16* g = qkv + (size_t)(t0 + row) * QKVN + VOFF + hk * DVH + ch * 8;
    uint2 a = *(const uint2*)g;
    uint2 b = *(const uint2*)(g + 4);
    *(uint2*)&tile[row][ch * 8] = a;
    *(uint2*)&tile[row][ch * 8 + 4] = b;
  }
  __syncthreads();
#pragma unroll
  for (int i = 0; i < 3; i++) {
    int idx = i * 256 + tid;
    int dv = idx >> 3, tc = (idx & 7) * 8;
    union { uint4 v4; u16 s[8]; } o;
#pragma unroll
    for (int j = 0; j < 8; j++) o.s[j] = tile[tc + j][dv];
    *(uint4*)(vt + (((size_t)(hk * 96 + dv)) << 12) + t0 + tc) = o.v4;
  }
}

// ---------------- MFMA sliding-window attention with sink ----------------
__global__ __launch_bounds__(256, 2) void attn_mfma(const u16* __restrict__ qkv,
                                                    const u16* __restrict__ vt,
                                                    const float* __restrict__ sink_bias,
                                                    u16* __restrict__ attn_out) {
  __shared__ u16 k_lds[64 * 128];
  __shared__ u16 v_lds[96 * 64];
  __shared__ u16 p_lds[4][2048];

  const int tid = threadIdx.x;
  const int wv = tid >> 6;
  const int lane = tid & 63;
  const int g = lane >> 4;
  const int c = lane & 15;
  const int t0 = blockIdx.x * 32;
  const int hk = blockIdx.y;
  const int h = hk * 4 + wv;

  bfrag8 qf[2][4];
#pragma unroll
  for (int m = 0; m < 2; m++)
#pragma unroll
    for (int kf = 0; kf < 4; kf++)
      qf[m][kf] = *(const bfrag8*)(qkv + (size_t)(t0 + m * 16 + c) * QKVN + h * DH + kf * 32 + g * 8);

  f32x4v acc_o[2][6];
#pragma unroll
  for (int m = 0; m < 2; m++)
#pragma unroll
    for (int n = 0; n < 6; n++) acc_o[m][n] = {0.f, 0.f, 0.f, 0.f};

  const float sb = sink_bias[h];
  float m_run[2][4], l_run[2][4];
#pragma unroll
  for (int m = 0; m < 2; m++)
#pragma unroll
    for (int r = 0; r < 4; r++) { m_run[m][r] = sb; l_run[m][r] = 1.0f; }

  int cb0 = t0 - (WWIN - 1);
  cb0 = (cb0 < 0) ? 0 : (cb0 & ~63);

  for (int cb = cb0; cb < t0 + 32; cb += 64) {
    __syncthreads();
#pragma unroll
    for (int it = 0; it < 4; it++) {
      int dest = it * 4096 + tid * 16;
      int row = dest >> 8;
      int src = dest ^ ((row & 7) << 4);
      const u16* gp = qkv + (size_t)(cb + row) * QKVN + KOFF + hk * DH + ((src & 255) >> 1);
      __builtin_amdgcn_global_load_lds((const __attribute__((address_space(1))) u32*)gp,
                                       (__attribute__((address_space(3))) u32*)((char*)k_lds + dest),
                                       16, 0, 0);
    }
#pragma unroll
    for (int it = 0; it < 3; it++) {
      int dest = it * 4096 + tid * 16;
      int row = dest >> 7;
      int src = dest ^ ((row & 7) << 4);
      const u16* gp = vt + (((size_t)(hk * 96 + row)) << 12) + cb + ((src & 127) >> 1);
      __builtin_amdgcn_global_load_lds((const __attribute__((address_space(1))) u32*)gp,
                                       (__attribute__((address_space(3))) u32*)((char*)v_lds + dest),
                                       16, 0, 0);
    }
    __syncthreads();

    f32x4v s[2][4];
#pragma unroll
    for (int m = 0; m < 2; m++)
#pragma unroll
      for (int n = 0; n < 4; n++) s[m][n] = {0.f, 0.f, 0.f, 0.f};
#pragma unroll
    for (int kf = 0; kf < 4; kf++) {
      bfrag8 kb[4];
#pragma unroll
      for (int n = 0; n < 4; n++) {
        int key = n * 16 + c;
        int byt = ((key << 8) + (kf << 6) + (g << 4)) ^ ((key & 7) << 4);
        kb[n] = *(const bfrag8*)((const char*)k_lds + byt);
      }
#pragma unroll
      for (int m = 0; m < 2; m++)
#pragma unroll
        for (int n = 0; n < 4; n++)
          s[m][n] = __builtin_amdgcn_mfma_f32_16x16x32_bf16(qf[m][kf], kb[n], s[m][n], 0, 0, 0);
    }

    if ((cb + 63 > t0) || (cb + WWIN < t0 + 32)) {
#pragma unroll
      for (int m = 0; m < 2; m++)
#pragma unroll
        for (int n = 0; n < 4; n++)
#pragma unroll
          for (int r = 0; r < 4; r++) {
            int rel = (t0 + m * 16 + g * 4 + r) - (cb + n * 16 + c);
            if (!(rel >= 0 && rel < WWIN)) s[m][n][r] = -3.0e38f;
          }
    }

    float corr[2][4];
#pragma unroll
    for (int m = 0; m < 2; m++)
#pragma unroll
      for (int r = 0; r < 4; r++) {
        float v0 = fmaxf(fmaxf(s[m][0][r], s[m][1][r]), fmaxf(s[m][2][r], s[m][3][r]));
        v0 = fmaxf(v0, __shfl_xor(v0, 1));
        v0 = fmaxf(v0, __shfl_xor(v0, 2));
        v0 = fmaxf(v0, __shfl_xor(v0, 4));
        v0 = fmaxf(v0, __shfl_xor(v0, 8));
        float mn = fmaxf(m_run[m][r], v0);
        corr[m][r] = __expf(m_run[m][r] - mn);
        m_run[m][r] = mn;
        float p0 = __expf(s[m][0][r] - mn);
        float p1 = __expf(s[m][1][r] - mn);
        float p2 = __expf(s[m][2][r] - mn);
        float p3 = __expf(s[m][3][r] - mn);
        s[m][0][r] = p0; s[m][1][r] = p1; s[m][2][r] = p2; s[m][3][r] = p3;
        float rs = p0 + p1 + p2 + p3;
        rs += __shfl_xor(rs, 1);
        rs += __shfl_xor(rs, 2);
        rs += __shfl_xor(rs, 4);
        rs += __shfl_xor(rs, 8);
        l_run[m][r] = l_run[m][r] * corr[m][r] + rs;
      }
#pragma unroll
    for (int m = 0; m < 2; m++)
#pragma unroll
      for (int n = 0; n < 6; n++)
#pragma unroll
      for (int r = 0; r < 4; r++) acc_o[m][n][r] *= corr[m][r];

#pragma unroll
    for (int m = 0; m < 2; m++)
#pragma unroll
      for (int n = 0; n < 4; n++) {
        u32 lo = (u32)f2bf(s[m][n][0]) | ((u32)f2bf(s[m][n][1]) << 16);
        u32 hi = (u32)f2bf(s[m][n][2]) | ((u32)f2bf(s[m][n][3]) << 16);
        int byt = ((m * 2 + (n >> 1)) << 10) | (g << 3) | ((c & 3) << 5) |
                  (((c >> 2) & 1) << 9) | ((((n & 1) * 2) + (c >> 3)) << 7);
        uint2 u; u.x = lo; u.y = hi;
        *(uint2*)((char*)&p_lds[wv][0] + byt) = u;
      }

#pragma unroll
    for (int ks = 0; ks < 2; ks++) {
      bfrag8 pa[2];
#pragma unroll
      for (int m = 0; m < 2; m++) {
        union { bfrag8 v; u16 s16[8]; } u;
#pragma unroll
        for (int j = 0; j < 4; j++) {
          int e = ((m * 2 + ks) << 9) + c + j * 16 + g * 64;
          u.s16[j] = p_lds[wv][e];
          u.s16[4 + j] = p_lds[wv][e + 256];
        }
        pa[m] = u.v;
      }
#pragma unroll
      for (int n = 0; n < 6; n++) {
        int dv = n * 16 + c;
        int byt = ((dv << 7) + (ks << 6) + (g << 4)) ^ ((dv & 7) << 4);
        bfrag8 vb = *(const bfrag8*)((const char*)v_lds + byt);
#pragma unroll
        for (int m = 0; m < 2; m++)
          acc_o[m][n] = __builtin_amdgcn_mfma_f32_16x16x32_bf16(pa[m], vb, acc_o[m][n], 0, 0, 0);
      }
    }
  }

#pragma unroll
  for (int m = 0; m < 2; m++) {
    float inv[4];
#pragma unroll
    for (int r = 0; r < 4; r++) inv[r] = 1.0f / l_run[m][r];
#pragma unroll
    for (int n = 0; n < 6; n++)
#pragma unroll
      for (int r = 0; r < 4; r++) {
        int tq = t0 + m * 16 + g * 4 + r;
        attn_out[(size_t)tq * ATTN + h * DVH + n * 16 + c] = f2bf(acc_o[m][n][r] * inv[r]);
      }
  }
}

// ---------------- launcher ----------------
extern "C" void kernel_launch(void* const* d_in, const int* in_sizes, int n_in,
                              void* d_out, int out_size, void* d_ws, size_t ws_size,
                              hipStream_t stream) {
  const int* positions = (const int*)d_in[0];
  const float* hidden = (const float*)d_in[1];
  const float* qkv_w = (const float*)d_in[2];
  const float* o_w = (const float*)d_in[3];
  const float* sink = (const float*)d_in[4];
  char* ws = (char*)d_ws;

  u16* hs_bf   = (u16*)(ws + 0);          // 16,777,216 B (dead after gemm1)
  u16* w1_bf   = (u16*)(ws + 16777216);   // 24,117,248 B (dead after gemm1)
  u16* attn_bf = (u16*)(ws + 0);          // 25,165,824 B (overlaps hs/w1)
  u16* vt_buf  = (u16*)(ws + 25165824);   //  6,291,456 B
  u16* w2_bf   = (u16*)(ws + 40894464);   // 12,582,912 B
  u16* qkv_bf  = (u16*)(ws + 53477376);   // 48,234,496 B

  // dynamic-LDS attribute (deterministic every call; fallback if unsupported)
  bool pipeOk =
    (hipFuncSetAttribute((const void*)&gemm_pipe<4, 0>,
                         hipFuncAttributeMaxDynamicSharedMemorySize, 98304) == hipSuccess) &&
    (hipFuncSetAttribute((const void*)&gemm_pipe<2, 1>,
                         hipFuncAttributeMaxDynamicSharedMemorySize, 73728) == hipSuccess);

  cvt_kernel<<<dim3(1024), dim3(256), 0, stream>>>(hidden, hs_bf, 8388608 / 4);
  cvt_kernel<<<dim3(1024), dim3(256), 0, stream>>>(qkv_w, w1_bf, 12058624 / 4);
  cvt_kernel<<<dim3(1024), dim3(256), 0, stream>>>(o_w, w2_bf, 6291456 / 4);

  if (pipeOk)
    gemm_pipe<4, 0><<<dim3(368), dim3(512), 98304, stream>>>(hs_bf, w1_bf, (void*)qkv_bf,
                                                             T_SEQ, QKVN, HIDDEN, 16);
  else
    gemm_nt<0><<<dim3(32, 46), dim3(256), 0, stream>>>(hs_bf, w1_bf, (void*)qkv_bf,
                                                       T_SEQ, QKVN, HIDDEN);

  rope_kernel<<<dim3(40960), dim3(256), 0, stream>>>(qkv_bf, positions);
  vt_kernel<<<dim3(T_SEQ / 64, NKVH), dim3(256), 0, stream>>>(qkv_bf, vt_buf);
  attn_mfma<<<dim3(T_SEQ / 32, NKVH), dim3(256), 0, stream>>>(qkv_bf, vt_buf, sink, attn_bf);

  if (pipeOk)
    gemm_pipe<2, 1><<<dim3(256), dim3(512), 73728, stream>>>(attn_bf, w2_bf, d_out,
                                                             T_SEQ, HIDDEN, ATTN, 16);
  else
    gemm_nt<1><<<dim3(32, 16), dim3(256), 0, stream>>>(attn_bf, w2_bf, d_out,
                                                       T_SEQ, HIDDEN, ATTN);
}

// Round 4
// 321.287 us; speedup vs baseline: 3.5017x; 1.0047x over previous
//
#include <hip/hip_runtime.h>
#include <hip/hip_bf16.h>
#include <stdint.h>

#define T_SEQ 4096
#define HIDDEN 2048
#define NQH 32
#define NKVH 8
#define DH 128
#define DVH 96
#define WWIN 512
#define QKVN 5888           // 32*128 + 8*128 + 8*96
#define KOFF 4096
#define VOFF 5120
#define ATTN 3072           // 32*96
#define QSCALE 0.08838834764831845f  // 128^-0.5

typedef uint16_t u16;
typedef uint32_t u32;
typedef __bf16 bfrag8 __attribute__((ext_vector_type(8)));
typedef float f32x4v __attribute__((ext_vector_type(4)));

__device__ __forceinline__ u16 f2bf(float x) {
  u32 u = __float_as_uint(x);
  return (u16)((u + 0x7fffu + ((u >> 16) & 1u)) >> 16);
}
__device__ __forceinline__ float bf2f(u16 v) { return __uint_as_float(((u32)v) << 16); }

// ---------------- f32 -> bf16 bulk convert ----------------
__global__ void cvt_kernel(const float* __restrict__ in, u16* __restrict__ out, int n4) {
  int i = blockIdx.x * blockDim.x + threadIdx.x;
  int st = gridDim.x * blockDim.x;
  for (; i < n4; i += st) {
    float4 v = ((const float4*)in)[i];
    ushort4 o;
    o.x = f2bf(v.x); o.y = f2bf(v.y); o.z = f2bf(v.z); o.w = f2bf(v.w);
    ((ushort4*)out)[i] = o;
  }
}

// =======================================================================
// 8-phase 256x256 bf16 NT GEMM (m201-style port): C[M][N] = A[M][K]*B[N][K]^T
// BK=64, 8 waves (2M x 4N, per-wave 128x64), LDS = 2 buf x 4 halves x 16 KB.
// Per K-tile: 4 phases, each {ds_read subtile | stage next halves | barrier |
// lgkmcnt(0) | setprio(1) 16 MFMA setprio(0) | barrier}. One counted
// vmcnt(4) per tile (never 0 in steady state): issued-next-A stays in
// flight; per-wave vmcnt + barrier => tile-t LDS complete chip-wide.
// Clobber proof: tile t+1 stages write buf((t+1)&1) = tile t-1's buffer,
// fully consumed before t-1's final barrier. LDS rows 128 B, XOR swizzle
// byte ^= ((row&7)<<4); staging pre-applies inverse on global source.
// =======================================================================
__global__ __launch_bounds__(512, 2) void gemm_8p(const u16* __restrict__ A,
                                                  const u16* __restrict__ B,
                                                  u16* __restrict__ C,
                                                  int M, int N, int K, int nbm) {
  extern __shared__ u16 lds[];   // 2 x 32768 u16 (128 KB)
  const int tid = threadIdx.x;
  const int w = tid >> 6, lane = tid & 63;
  const int wr = w >> 2, wc = w & 3;
  const int fr = lane & 15, kg = lane >> 4;

  const int nwg = gridDim.x;
  int bid = (int)blockIdx.x;
  if ((nwg & 7) == 0) bid = (bid & 7) * (nwg >> 3) + (bid >> 3);
  const int bm = (bid % nbm) * 256;
  const int bn = (bid / nbm) * 256;
  const int NT = K >> 6;

  f32x4v acc[8][4];
#pragma unroll
  for (int m = 0; m < 8; m++)
#pragma unroll
    for (int n = 0; n < 4; n++) acc[m][n] = {0.f, 0.f, 0.f, 0.f};

  // stage one 128x64 half-tile (16 KB); dest linear, source inverse-swizzled
  auto stageHalf = [&](const u16* rowbase, int kt, u16* dst) {
#pragma unroll
    for (int i = 0; i < 2; i++) {
      int D = (i * 512 + tid) * 16;
      int r = D >> 7;
      int kb = (D ^ ((r & 7) << 4)) & 127;
      const u16* gp = rowbase + (size_t)r * K + kt + (kb >> 1);
      __builtin_amdgcn_global_load_lds((const __attribute__((address_space(1))) u32*)gp,
                                       (__attribute__((address_space(3))) u32*)((char*)dst + D),
                                       16, 0, 0);
    }
  };

  const u16* Arow0 = A + (size_t)bm * K;
  const u16* Arow1 = A + (size_t)(bm + 128) * K;
  const u16* Brow0 = B + (size_t)bn * K;
  const u16* Brow1 = B + (size_t)(bn + 128) * K;

  // prologue: tile 0 -> buf 0 (8 loads/thread)
  stageHalf(Arow0, 0, lds);
  stageHalf(Arow1, 0, lds + 8192);
  stageHalf(Brow0, 0, lds + 16384);
  stageHalf(Brow1, 0, lds + 24576);

  const int bcol = (wc & 1) * 64;   // local col base within my B-half

  for (int t = 0; t < NT; ++t) {
    u16* buf = lds + (t & 1) * 32768;
    u16* nbuf = lds + ((t + 1) & 1) * 32768;
    const u16* Ah = buf + wr * 8192;                  // my A-half (128x64)
    const u16* Bh = buf + 16384 + (wc >> 1) * 8192;   // my B-half (128x64)

    bfrag8 ar[4][2], br[4][2];

    // ---------------- phase 0 ----------------
    if (t + 1 < NT) {
      stageHalf(Arow0, (t + 1) << 6, nbuf);
      stageHalf(Arow1, (t + 1) << 6, nbuf + 8192);
      asm volatile("s_waitcnt vmcnt(4)");
    } else {
      asm volatile("s_waitcnt vmcnt(0)");
    }
    asm volatile("s_barrier" ::: "memory");
    // ds: A rows 0-63 (8) + B cols bcol..+31 (4)
#pragma unroll
    for (int rb = 0; rb < 4; rb++)
#pragma unroll
      for (int ks = 0; ks < 2; ks++) {
        int row = rb * 16 + fr;
        int byt = ((row << 7) | (ks << 6) | (kg << 4)) ^ ((row & 7) << 4);
        ar[rb][ks] = *(const bfrag8*)((const char*)Ah + byt);
      }
#pragma unroll
    for (int nb = 0; nb < 2; nb++)
#pragma unroll
      for (int ks = 0; ks < 2; ks++) {
        int col = bcol + nb * 16 + fr;
        int byt = ((col << 7) | (ks << 6) | (kg << 4)) ^ ((col & 7) << 4);
        br[nb][ks] = *(const bfrag8*)((const char*)Bh + byt);
      }
    asm volatile("s_waitcnt lgkmcnt(0)" ::: "memory");
    __builtin_amdgcn_sched_barrier(0);
    __builtin_amdgcn_s_setprio(1);
#pragma unroll
    for (int rb = 0; rb < 4; rb++)
#pragma unroll
      for (int nb = 0; nb < 2; nb++)
#pragma unroll
        for (int ks = 0; ks < 2; ks++)
          acc[rb][nb] = __builtin_amdgcn_mfma_f32_16x16x32_bf16(ar[rb][ks], br[nb][ks], acc[rb][nb], 0, 0, 0);
    __builtin_amdgcn_s_setprio(0);
    asm volatile("s_barrier" ::: "memory");

    // ---------------- phase 1 ----------------
#pragma unroll
    for (int nb = 2; nb < 4; nb++)
#pragma unroll
      for (int ks = 0; ks < 2; ks++) {
        int col = bcol + nb * 16 + fr;
        int byt = ((col << 7) | (ks << 6) | (kg << 4)) ^ ((col & 7) << 4);
        br[nb][ks] = *(const bfrag8*)((const char*)Bh + byt);
      }
    if (t + 1 < NT) {
      stageHalf(Brow0, (t + 1) << 6, nbuf + 16384);
      stageHalf(Brow1, (t + 1) << 6, nbuf + 24576);
    }
    asm volatile("s_barrier" ::: "memory");
    asm volatile("s_waitcnt lgkmcnt(0)" ::: "memory");
    __builtin_amdgcn_sched_barrier(0);
    __builtin_amdgcn_s_setprio(1);
#pragma unroll
    for (int rb = 0; rb < 4; rb++)
#pragma unroll
      for (int nb = 2; nb < 4; nb++)
#pragma unroll
        for (int ks = 0; ks < 2; ks++)
          acc[rb][nb] = __builtin_amdgcn_mfma_f32_16x16x32_bf16(ar[rb][ks], br[nb][ks], acc[rb][nb], 0, 0, 0);
    __builtin_amdgcn_s_setprio(0);
    asm volatile("s_barrier" ::: "memory");

    // ---------------- phase 2 ----------------
#pragma unroll
    for (int rb = 0; rb < 4; rb++)
#pragma unroll
      for (int ks = 0; ks < 2; ks++) {
        int row = 64 + rb * 16 + fr;
        int byt = ((row << 7) | (ks << 6) | (kg << 4)) ^ ((row & 7) << 4);
        ar[rb][ks] = *(const bfrag8*)((const char*)Ah + byt);
      }
    asm volatile("s_barrier" ::: "memory");
    asm volatile("s_waitcnt lgkmcnt(0)" ::: "memory");
    __builtin_amdgcn_sched_barrier(0);
    __builtin_amdgcn_s_setprio(1);
#pragma unroll
    for (int rb = 0; rb < 4; rb++)
#pragma unroll
      for (int nb = 0; nb < 2; nb++)
#pragma unroll
        for (int ks = 0; ks < 2; ks++)
          acc[4 + rb][nb] = __builtin_amdgcn_mfma_f32_16x16x32_bf16(ar[rb][ks], br[nb][ks], acc[4 + rb][nb], 0, 0, 0);
    __builtin_amdgcn_s_setprio(0);
    asm volatile("s_barrier" ::: "memory");

    // ---------------- phase 3 ----------------
    __builtin_amdgcn_s_setprio(1);
#pragma unroll
    for (int rb = 0; rb < 4; rb++)
#pragma unroll
      for (int nb = 2; nb < 4; nb++)
#pragma unroll
        for (int ks = 0; ks < 2; ks++)
          acc[4 + rb][nb] = __builtin_amdgcn_mfma_f32_16x16x32_bf16(ar[rb][ks], br[nb][ks], acc[4 + rb][nb], 0, 0, 0);
    __builtin_amdgcn_s_setprio(0);
    asm volatile("s_barrier" ::: "memory");
  }

  // epilogue: C-write (frag layout: row = kg*4+r, col = fr)
  const int rb0 = bm + wr * 128;
  const int cb0 = bn + wc * 64;
#pragma unroll
  for (int m = 0; m < 8; m++)
#pragma unroll
    for (int n = 0; n < 4; n++) {
      size_t base = (size_t)(rb0 + m * 16 + kg * 4) * N + cb0 + n * 16 + fr;
#pragma unroll
      for (int r = 0; r < 4; r++)
        C[base + (size_t)r * N] = f2bf(acc[m][n][r]);
    }
}

// ---------------- round-3 pipelined GEMM (kept for gemm2) ----------------
template<int WN, int OUT_F32>
__global__ __launch_bounds__(512, 2) void gemm_pipe(const u16* __restrict__ A,
                                                    const u16* __restrict__ B,
                                                    void* __restrict__ Cp,
                                                    int M, int N, int K, int nbm) {
  constexpr int BN = WN * 64;
  constexpr int WM = 8 / WN;
  constexpr int MF = 16 / WM;
  constexpr int ASZ = 8192;
  constexpr int BSZ = BN * 32;
  constexpr int BUFSZ = ASZ + BSZ;
  constexpr int AIN = 2;
  constexpr int BIN = (WN == 4) ? 2 : 1;
  constexpr int LPT = AIN + BIN;

  extern __shared__ u16 lds[];

  const int tid = threadIdx.x;
  const int w = tid >> 6, lane = tid & 63;
  const int wr = w / WN, wc = w % WN;
  const int fr = lane & 15, kg = lane >> 4;

  const int nwg = gridDim.x;
  int bid = (int)blockIdx.x;
  if ((nwg & 7) == 0) bid = (bid & 7) * (nwg >> 3) + (bid >> 3);
  const int bm = (bid % nbm) * 256;
  const int bn = (bid / nbm) * BN;

  const int NT = K >> 5;

  f32x4v acc[MF][4];
#pragma unroll
  for (int m = 0; m < MF; m++)
#pragma unroll
    for (int n = 0; n < 4; n++) acc[m][n] = {0.f, 0.f, 0.f, 0.f};

  auto stageA = [&](int t) {
    u16* dst = lds + (t % 3) * BUFSZ;
#pragma unroll
    for (int i = 0; i < AIN; i++) {
      int D = (w * AIN + i) * 1024 + lane * 16;
      int srow = D >> 7;
      int Dx = D ^ ((srow & 7) << 4);
      int c = (Dx >> 1) & 63;
      int m = 2 * srow + (c >> 5);
      int k = c & 31;
      const u16* src = A + (size_t)(bm + m) * K + (t << 5) + k;
      __builtin_amdgcn_global_load_lds((const __attribute__((address_space(1))) u32*)src,
                                       (__attribute__((address_space(3))) u32*)((char*)dst + D),
                                       16, 0, 0);
    }
  };
  auto stageB = [&](int t) {
    u16* dst = lds + (t % 3) * BUFSZ + ASZ;
#pragma unroll
    for (int i = 0; i < BIN; i++) {
      int D = (w * BIN + i) * 1024 + lane * 16;
      int srow = D >> 7;
      int Dx = D ^ ((srow & 7) << 4);
      int c = (Dx >> 1) & 63;
      int m = 2 * srow + (c >> 5);
      int k = c & 31;
      const u16* src = B + (size_t)(bn + m) * K + (t << 5) + k;
      __builtin_amdgcn_global_load_lds((const __attribute__((address_space(1))) u32*)src,
                                       (__attribute__((address_space(3))) u32*)((char*)dst + D),
                                       16, 0, 0);
    }
  };

  stageA(0); stageB(0);
  stageA(1); stageB(1);

  for (int t = 0; t < NT; ++t) {
    const u16* At = lds + (t % 3) * BUFSZ;
    const u16* Bt = At + ASZ;
    if (t + 1 < NT) asm volatile("s_waitcnt vmcnt(%0)" :: "n"(LPT));
    else            asm volatile("s_waitcnt vmcnt(0)");
    asm volatile("s_barrier" ::: "memory");

    bfrag8 bfr[4];
#pragma unroll
    for (int n = 0; n < 4; n++) {
      int nr = wc * 64 + n * 16 + fr;
      int byt = (((nr >> 1) << 7) + ((nr & 1) << 6) + (kg << 4)) ^ (((nr >> 1) & 7) << 4);
      bfr[n] = *(const bfrag8*)((const char*)Bt + byt);
    }
    bfrag8 afr[MF / 2];
#pragma unroll
    for (int m = 0; m < MF / 2; m++) {
      int mr = wr * (MF * 16) + m * 16 + fr;
      int byt = (((mr >> 1) << 7) + ((mr & 1) << 6) + (kg << 4)) ^ (((mr >> 1) & 7) << 4);
      afr[m] = *(const bfrag8*)((const char*)At + byt);
    }
    if (t + 2 < NT) stageA(t + 2);
    __builtin_amdgcn_s_setprio(1);
#pragma unroll
    for (int m = 0; m < MF / 2; m++)
#pragma unroll
      for (int n = 0; n < 4; n++)
        acc[m][n] = __builtin_amdgcn_mfma_f32_16x16x32_bf16(afr[m], bfr[n], acc[m][n], 0, 0, 0);
    __builtin_amdgcn_s_setprio(0);
    asm volatile("s_barrier" ::: "memory");

    bfrag8 afr2[MF / 2];
#pragma unroll
    for (int m = 0; m < MF / 2; m++) {
      int mr = wr * (MF * 16) + (m + MF / 2) * 16 + fr;
      int byt = (((mr >> 1) << 7) + ((mr & 1) << 6) + (kg << 4)) ^ (((mr >> 1) & 7) << 4);
      afr2[m] = *(const bfrag8*)((const char*)At + byt);
    }
    if (t + 2 < NT) stageB(t + 2);
    __builtin_amdgcn_s_setprio(1);
#pragma unroll
    for (int m = 0; m < MF / 2; m++)
#pragma unroll
      for (int n = 0; n < 4; n++)
        acc[m + MF / 2][n] = __builtin_amdgcn_mfma_f32_16x16x32_bf16(afr2[m], bfr[n], acc[m + MF / 2][n], 0, 0, 0);
    __builtin_amdgcn_s_setprio(0);
  }

  const int rb = bm + wr * (MF * 16);
  const int cb = bn + wc * 64;
#pragma unroll
  for (int m = 0; m < MF; m++)
#pragma unroll
    for (int n = 0; n < 4; n++) {
      size_t base = (size_t)(rb + m * 16 + kg * 4) * N + cb + n * 16 + fr;
#pragma unroll
      for (int r = 0; r < 4; r++) {
        if (OUT_F32) ((float*)Cp)[base + (size_t)r * N] = acc[m][n][r];
        else         ((u16*)Cp)[base + (size_t)r * N] = f2bf(acc[m][n][r]);
      }
    }
}

// ---------------- fallback bf16 NT GEMM (round-2 proven) ----------------
template<int OUT_F32>
__global__ __launch_bounds__(256) void gemm_nt(const u16* __restrict__ A,
                                               const u16* __restrict__ B,
                                               void* __restrict__ Cp,
                                               int M, int N, int K) {
  __shared__ u16 Asm[128 * 32];
  __shared__ u16 Bsm[128 * 32];
  const int tid = threadIdx.x;
  const int wv = tid >> 6, lane = tid & 63;
  const int bm = blockIdx.x * 128, bn = blockIdx.y * 128;
  const int wm = (wv >> 1) * 64, wn = (wv & 1) * 64;
  const int srow = lane >> 2;
  const int scol = (lane & 3) * 8;
  const int fr = lane & 15, fk = (lane >> 4) * 8;
  f32x4v acc[4][4];
#pragma unroll
  for (int i = 0; i < 4; i++)
#pragma unroll
    for (int j = 0; j < 4; j++) acc[i][j] = {0.f, 0.f, 0.f, 0.f};

  for (int kt = 0; kt < K; kt += 32) {
    __syncthreads();
#pragma unroll
    for (int c = 0; c < 2; c++) {
      const int ci = wv * 2 + c;
      const u16* ga = A + (size_t)(bm + ci * 16 + srow) * K + kt + scol;
      const u16* gb = B + (size_t)(bn + ci * 16 + srow) * K + kt + scol;
      __builtin_amdgcn_global_load_lds((const __attribute__((address_space(1))) u32*)ga,
                                       (__attribute__((address_space(3))) u32*)(Asm + ci * 512),
                                       16, 0, 0);
      __builtin_amdgcn_global_load_lds((const __attribute__((address_space(1))) u32*)gb,
                                       (__attribute__((address_space(3))) u32*)(Bsm + ci * 512),
                                       16, 0, 0);
    }
    __syncthreads();
    bfrag8 af[4], bf[4];
#pragma unroll
    for (int i = 0; i < 4; i++) af[i] = *(const bfrag8*)(Asm + (wm + i * 16 + fr) * 32 + fk);
#pragma unroll
    for (int j = 0; j < 4; j++) bf[j] = *(const bfrag8*)(Bsm + (wn + j * 16 + fr) * 32 + fk);
#pragma unroll
    for (int i = 0; i < 4; i++)
#pragma unroll
      for (int j = 0; j < 4; j++)
        acc[i][j] = __builtin_amdgcn_mfma_f32_16x16x32_bf16(af[i], bf[j], acc[i][j], 0, 0, 0);
  }
  const int orow = (lane >> 4) * 4, ocol = lane & 15;
#pragma unroll
  for (int i = 0; i < 4; i++)
#pragma unroll
    for (int j = 0; j < 4; j++) {
      size_t base = (size_t)(bm + wm + i * 16 + orow) * N + (size_t)(bn + wn + j * 16 + ocol);
#pragma unroll
      for (int r = 0; r < 4; r++) {
        if (OUT_F32) ((float*)Cp)[base + (size_t)r * N] = acc[i][j][r];
        else         ((u16*)Cp)[base + (size_t)r * N] = f2bf(acc[i][j][r]);
      }
    }
}

// ---------------- RoPE in-place on q,k (q also pre-scaled) ----------------
__global__ void rope_kernel(u16* __restrict__ qkv, const int* __restrict__ pos) {
  int gid = blockIdx.x * 256 + threadIdx.x;
  int d = gid & 63;
  int r = gid >> 6;
  int hh = r % 40;
  int t = r / 40;
  if (t >= T_SEQ) return;
  int off = (hh < 32) ? hh * 128 : KOFF + (hh - 32) * 128;
  u16* p = qkv + (size_t)t * QKVN + off + d;
  float x1 = bf2f(p[0]);
  float x2 = bf2f(p[64]);
  float inv_freq = exp2f(-(float)d * 0.3114307588956852f);
  float ang = (float)pos[t] * inv_freq;
  float c = cosf(ang), s = sinf(ang);
  float y1 = x1 * c - x2 * s;
  float y2 = x2 * c + x1 * s;
  if (hh < 32) { y1 *= QSCALE; y2 *= QSCALE; }
  p[0] = f2bf(y1);
  p[64] = f2bf(y2);
}

// ---------------- V transpose: qkv V region -> vt[hk][dv][t] ----------------
__global__ __launch_bounds__(256) void vt_kernel(const u16* __restrict__ qkv,
                                                 u16* __restrict__ vt) {
  __shared__ u16 tile[64][100];
  const int t0 = blockIdx.x * 64;
  const int hk = blockIdx.y;
  const int tid = threadIdx.x;
#pragma unroll
  for (int i = 0; i < 3; i++) {
    int idx = i * 256 + tid;
    int row = idx / 12, ch = idx % 12;
    const u16* g = qkv + (size_t)(t0 + row) * QKVN + VOFF + hk * DVH + ch * 8;
    uint2 a = *(const uint2*)g;
    uint2 b = *(const uint2*)(g + 4);
    *(uint2*)&tile[row][ch * 8] = a;
    *(uint2*)&tile[row][ch * 8 + 4] = b;
  }
  __syncthreads();
#pragma unroll
  for (int i = 0; i < 3; i++) {
    int idx = i * 256 + tid;
    int dv = idx >> 3, tc = (idx & 7) * 8;
    union { uint4 v4; u16 s[8]; } o;
#pragma unroll
    for (int j = 0; j < 8; j++) o.s[j] = tile[tc + j][dv];
    *(uint4*)(vt + (((size_t)(hk * 96 + dv)) << 12) + t0 + tc) = o.v4;
  }
}

// ---------------- MFMA sliding-window attention with sink ----------------
__global__ __launch_bounds__(256, 2) void attn_mfma(const u16* __restrict__ qkv,
                                                    const u16* __restrict__ vt,
                                                    const float* __restrict__ sink_bias,
                                                    u16* __restrict__ attn_out) {
  __shared__ u16 k_lds[64 * 128];
  __shared__ u16 v_lds[96 * 64];
  __shared__ u16 p_lds[4][2048];

  const int tid = threadIdx.x;
  const int wv = tid >> 6;
  const int lane = tid & 63;
  const int g = lane >> 4;
  const int c = lane & 15;
  const int t0 = blockIdx.x * 32;
  const int hk = blockIdx.y;
  const int h = hk * 4 + wv;

  bfrag8 qf[2][4];
#pragma unroll
  for (int m = 0; m < 2; m++)
#pragma unroll
    for (int kf = 0; kf < 4; kf++)
      qf[m][kf] = *(const bfrag8*)(qkv + (size_t)(t0 + m * 16 + c) * QKVN + h * DH + kf * 32 + g * 8);

  f32x4v acc_o[2][6];
#pragma unroll
  for (int m = 0; m < 2; m++)
#pragma unroll
    for (int n = 0; n < 6; n++) acc_o[m][n] = {0.f, 0.f, 0.f, 0.f};

  const float sb = sink_bias[h];
  float m_run[2][4], l_run[2][4];
#pragma unroll
  for (int m = 0; m < 2; m++)
#pragma unroll
    for (int r = 0; r < 4; r++) { m_run[m][r] = sb; l_run[m][r] = 1.0f; }

  int cb0 = t0 - (WWIN - 1);
  cb0 = (cb0 < 0) ? 0 : (cb0 & ~63);

  for (int cb = cb0; cb < t0 + 32; cb += 64) {
    __syncthreads();
#pragma unroll
    for (int it = 0; it < 4; it++) {
      int dest = it * 4096 + tid * 16;
      int row = dest >> 8;
      int src = dest ^ ((row & 7) << 4);
      const u16* gp = qkv + (size_t)(cb + row) * QKVN + KOFF + hk * DH + ((src & 255) >> 1);
      __builtin_amdgcn_global_load_lds((const __attribute__((address_space(1))) u32*)gp,
                                       (__attribute__((address_space(3))) u32*)((char*)k_lds + dest),
                                       16, 0, 0);
    }
#pragma unroll
    for (int it = 0; it < 3; it++) {
      int dest = it * 4096 + tid * 16;
      int row = dest >> 7;
      int src = dest ^ ((row & 7) << 4);
      const u16* gp = vt + (((size_t)(hk * 96 + row)) << 12) + cb + ((src & 127) >> 1);
      __builtin_amdgcn_global_load_lds((const __attribute__((address_space(1))) u32*)gp,
                                       (__attribute__((address_space(3))) u32*)((char*)v_lds + dest),
                                       16, 0, 0);
    }
    __syncthreads();

    f32x4v s[2][4];
#pragma unroll
    for (int m = 0; m < 2; m++)
#pragma unroll
      for (int n = 0; n < 4; n++) s[m][n] = {0.f, 0.f, 0.f, 0.f};
#pragma unroll
    for (int kf = 0; kf < 4; kf++) {
      bfrag8 kb[4];
#pragma unroll
      for (int n = 0; n < 4; n++) {
        int key = n * 16 + c;
        int byt = ((key << 8) + (kf << 6) + (g << 4)) ^ ((key & 7) << 4);
        kb[n] = *(const bfrag8*)((const char*)k_lds + byt);
      }
#pragma unroll
      for (int m = 0; m < 2; m++)
#pragma unroll
        for (int n = 0; n < 4; n++)
          s[m][n] = __builtin_amdgcn_mfma_f32_16x16x32_bf16(qf[m][kf], kb[n], s[m][n], 0, 0, 0);
    }

    if ((cb + 63 > t0) || (cb + WWIN < t0 + 32)) {
#pragma unroll
      for (int m = 0; m < 2; m++)
#pragma unroll
        for (int n = 0; n < 4; n++)
#pragma unroll
          for (int r = 0; r < 4; r++) {
            int rel = (t0 + m * 16 + g * 4 + r) - (cb + n * 16 + c);
            if (!(rel >= 0 && rel < WWIN)) s[m][n][r] = -3.0e38f;
          }
    }

    float corr[2][4];
#pragma unroll
    for (int m = 0; m < 2; m++)
#pragma unroll
      for (int r = 0; r < 4; r++) {
        float v0 = fmaxf(fmaxf(s[m][0][r], s[m][1][r]), fmaxf(s[m][2][r], s[m][3][r]));
        v0 = fmaxf(v0, __shfl_xor(v0, 1));
        v0 = fmaxf(v0, __shfl_xor(v0, 2));
        v0 = fmaxf(v0, __shfl_xor(v0, 4));
        v0 = fmaxf(v0, __shfl_xor(v0, 8));
        float mn = fmaxf(m_run[m][r], v0);
        corr[m][r] = __expf(m_run[m][r] - mn);
        m_run[m][r] = mn;
        float p0 = __expf(s[m][0][r] - mn);
        float p1 = __expf(s[m][1][r] - mn);
        float p2 = __expf(s[m][2][r] - mn);
        float p3 = __expf(s[m][3][r] - mn);
        s[m][0][r] = p0; s[m][1][r] = p1; s[m][2][r] = p2; s[m][3][r] = p3;
        float rs = p0 + p1 + p2 + p3;
        rs += __shfl_xor(rs, 1);
        rs += __shfl_xor(rs, 2);
        rs += __shfl_xor(rs, 4);
        rs += __shfl_xor(rs, 8);
        l_run[m][r] = l_run[m][r] * corr[m][r] + rs;
      }
#pragma unroll
    for (int m = 0; m < 2; m++)
#pragma unroll
      for (int n = 0; n < 6; n++)
#pragma unroll
      for (int r = 0; r < 4; r++) acc_o[m][n][r] *= corr[m][r];

#pragma unroll
    for (int m = 0; m < 2; m++)
#pragma unroll
      for (int n = 0; n < 4; n++) {
        u32 lo = (u32)f2bf(s[m][n][0]) | ((u32)f2bf(s[m][n][1]) << 16);
        u32 hi = (u32)f2bf(s[m][n][2]) | ((u32)f2bf(s[m][n][3]) << 16);
        int byt = ((m * 2 + (n >> 1)) << 10) | (g << 3) | ((c & 3) << 5) |
                  (((c >> 2) & 1) << 9) | ((((n & 1) * 2) + (c >> 3)) << 7);
        uint2 u; u.x = lo; u.y = hi;
        *(uint2*)((char*)&p_lds[wv][0] + byt) = u;
      }

#pragma unroll
    for (int ks = 0; ks < 2; ks++) {
      bfrag8 pa[2];
#pragma unroll
      for (int m = 0; m < 2; m++) {
        union { bfrag8 v; u16 s16[8]; } u;
#pragma unroll
        for (int j = 0; j < 4; j++) {
          int e = ((m * 2 + ks) << 9) + c + j * 16 + g * 64;
          u.s16[j] = p_lds[wv][e];
          u.s16[4 + j] = p_lds[wv][e + 256];
        }
        pa[m] = u.v;
      }
#pragma unroll
      for (int n = 0; n < 6; n++) {
        int dv = n * 16 + c;
        int byt = ((dv << 7) + (ks << 6) + (g << 4)) ^ ((dv & 7) << 4);
        bfrag8 vb = *(const bfrag8*)((const char*)v_lds + byt);
#pragma unroll
        for (int m = 0; m < 2; m++)
          acc_o[m][n] = __builtin_amdgcn_mfma_f32_16x16x32_bf16(pa[m], vb, acc_o[m][n], 0, 0, 0);
      }
    }
  }

#pragma unroll
  for (int m = 0; m < 2; m++) {
    float inv[4];
#pragma unroll
    for (int r = 0; r < 4; r++) inv[r] = 1.0f / l_run[m][r];
#pragma unroll
    for (int n = 0; n < 6; n++)
#pragma unroll
      for (int r = 0; r < 4; r++) {
        int tq = t0 + m * 16 + g * 4 + r;
        attn_out[(size_t)tq * ATTN + h * DVH + n * 16 + c] = f2bf(acc_o[m][n][r] * inv[r]);
      }
  }
}

// ---------------- launcher ----------------
extern "C" void kernel_launch(void* const* d_in, const int* in_sizes, int n_in,
                              void* d_out, int out_size, void* d_ws, size_t ws_size,
                              hipStream_t stream) {
  const int* positions = (const int*)d_in[0];
  const float* hidden = (const float*)d_in[1];
  const float* qkv_w = (const float*)d_in[2];
  const float* o_w = (const float*)d_in[3];
  const float* sink = (const float*)d_in[4];
  char* ws = (char*)d_ws;

  u16* hs_bf   = (u16*)(ws + 0);          // 16,777,216 B (dead after gemm1)
  u16* w1_bf   = (u16*)(ws + 16777216);   // 24,117,248 B (dead after gemm1)
  u16* attn_bf = (u16*)(ws + 0);          // 25,165,824 B (overlaps hs/w1)
  u16* vt_buf  = (u16*)(ws + 25165824);   //  6,291,456 B
  u16* w2_bf   = (u16*)(ws + 40894464);   // 12,582,912 B
  u16* qkv_bf  = (u16*)(ws + 53477376);   // 48,234,496 B

  bool p1Ok = (hipFuncSetAttribute((const void*)&gemm_8p,
                 hipFuncAttributeMaxDynamicSharedMemorySize, 131072) == hipSuccess);
  bool p2Ok = (hipFuncSetAttribute((const void*)&gemm_pipe<2, 1>,
                 hipFuncAttributeMaxDynamicSharedMemorySize, 73728) == hipSuccess);

  cvt_kernel<<<dim3(1024), dim3(256), 0, stream>>>(hidden, hs_bf, 8388608 / 4);
  cvt_kernel<<<dim3(1024), dim3(256), 0, stream>>>(qkv_w, w1_bf, 12058624 / 4);
  cvt_kernel<<<dim3(1024), dim3(256), 0, stream>>>(o_w, w2_bf, 6291456 / 4);

  if (p1Ok)
    gemm_8p<<<dim3(368), dim3(512), 131072, stream>>>(hs_bf, w1_bf, qkv_bf,
                                                      T_SEQ, QKVN, HIDDEN, 16);
  else
    gemm_nt<0><<<dim3(32, 46), dim3(256), 0, stream>>>(hs_bf, w1_bf, (void*)qkv_bf,
                                                       T_SEQ, QKVN, HIDDEN);

  rope_kernel<<<dim3(40960), dim3(256), 0, stream>>>(qkv_bf, positions);
  vt_kernel<<<dim3(T_SEQ / 64, NKVH), dim3(256), 0, stream>>>(qkv_bf, vt_buf);
  attn_mfma<<<dim3(T_SEQ / 32, NKVH), dim3(256), 0, stream>>>(qkv_bf, vt_buf, sink, attn_bf);

  if (p2Ok)
    gemm_pipe<2, 1><<<dim3(256), dim3(512), 73728, stream>>>(attn_bf, w2_bf, d_out,
                                                             T_SEQ, HIDDEN, ATTN, 16);
  else
    gemm_nt<1><<<dim3(32, 16), dim3(256), 0, stream>>>(attn_bf, w2_bf, d_out,
                                                       T_SEQ, HIDDEN, ATTN);
}

// Round 5
// 312.365 us; speedup vs baseline: 3.6017x; 1.0286x over previous
//
#include <hip/hip_runtime.h>
#include <hip/hip_bf16.h>
#include <stdint.h>

#define T_SEQ 4096
#define HIDDEN 2048
#define NQH 32
#define NKVH 8
#define DH 128
#define DVH 96
#define WWIN 512
#define QKVN 5888           // 32*128 + 8*128 + 8*96
#define KOFF 4096
#define VOFF 5120
#define ATTN 3072           // 32*96
#define QSCALE 0.08838834764831845f  // 128^-0.5

typedef uint16_t u16;
typedef uint32_t u32;
typedef __bf16 bfrag8 __attribute__((ext_vector_type(8)));
typedef float f32x4v __attribute__((ext_vector_type(4)));
typedef float f32x16 __attribute__((ext_vector_type(16)));

__device__ __forceinline__ u16 f2bf(float x) {
  u32 u = __float_as_uint(x);
  return (u16)((u + 0x7fffu + ((u >> 16) & 1u)) >> 16);
}
__device__ __forceinline__ float bf2f(u16 v) { return __uint_as_float(((u32)v) << 16); }

__device__ __forceinline__ void gload16(const u16* src, char* ldst) {
  __builtin_amdgcn_global_load_lds((const __attribute__((address_space(1))) u32*)src,
                                   (__attribute__((address_space(3))) u32*)ldst, 16, 0, 0);
}

// ---------------- f32 -> bf16 bulk convert ----------------
__global__ void cvt_kernel(const float* __restrict__ in, u16* __restrict__ out, int n4) {
  int i = blockIdx.x * blockDim.x + threadIdx.x;
  int st = gridDim.x * blockDim.x;
  for (; i < n4; i += st) {
    float4 v = ((const float4*)in)[i];
    ushort4 o;
    o.x = f2bf(v.x); o.y = f2bf(v.y); o.z = f2bf(v.z); o.w = f2bf(v.w);
    ((ushort4*)out)[i] = o;
  }
}

// =======================================================================
// GEMM core v3: C[M][N] = A[M][K] * B[N][K]^T, bf16 in, bf16/f32 out.
// BM=256, BN=128, BK=64; 8 waves (4M x 2N), per-wave 64x64 via 2x2
// mfma_f32_32x32x16_bf16 x 4 ksteps. TRIPLE-buffered LDS (3 x 48 KB):
// stage(t+1) writes buf((t+1)%3); its last readers (tile t-2) finished
// before the (t-1)-entry barrier, and collective barriers bound wave skew
// to < 1 tile -> race-free pre-barrier staging. One s_barrier + one
// counted s_waitcnt vmcnt(6) per K-tile (all 6 next-tile loads stay in
// flight; drain only at the last tile). LDS rows 128 B, XOR swizzle
// physical = logical ^ ((row&7)<<4); staging pre-applies the inverse on
// the global source; reads use one loop-invariant lane term q with
// per-read constant XOR/adds (no per-tile VALU address recompute).
// =======================================================================
template<int OUT_F32>
__global__ __launch_bounds__(512, 2) void gemm_v3(const u16* __restrict__ A,
                                                  const u16* __restrict__ B,
                                                  void* __restrict__ Cp,
                                                  int M, int N, int K, int nbm) {
  extern __shared__ char lds[];   // 3 x 49152 B
  const int tid = threadIdx.x;
  const int w = tid >> 6, lane = tid & 63;
  const int wr = w >> 1, wc = w & 1;      // 4M x 2N wave grid
  const int r5 = lane & 31, kg = lane >> 5;

  const int nwg = gridDim.x;
  int bid = (int)blockIdx.x;
  if ((nwg & 7) == 0) bid = (bid & 7) * (nwg >> 3) + (bid >> 3);
  const int bm = (bid % nbm) * 256;
  const int bn = (bid / nbm) * 128;
  const int NT = K >> 6;

  f32x16 acc[2][2];
#pragma unroll
  for (int mb = 0; mb < 2; mb++)
#pragma unroll
    for (int nb = 0; nb < 2; nb++)
#pragma unroll
      for (int i = 0; i < 16; i++) acc[mb][nb][i] = 0.f;

  // loop-invariant lane term: physical = base + mb*4096 + (q ^ (ks<<5))
  const int q = r5 * 128 + ((kg ^ (r5 & 7)) << 4);

  auto stageA = [&](int t) {   // 256x64 A tile, 32 KB, 4 gloads/wave
    char* dst = lds + (t % 3) * 49152;
    const u16* Abase = A + (size_t)bm * K + ((size_t)t << 6);
#pragma unroll
    for (int i = 0; i < 4; i++) {
      int D = (w * 4 + i) * 1024 + lane * 16;
      int row = D >> 7;
      int kb = (D ^ ((row & 7) << 4)) & 127;
      gload16(Abase + (size_t)row * K + (kb >> 1), dst + D);
    }
  };
  auto stageB = [&](int t) {   // 128x64 B tile, 16 KB, 2 gloads/wave
    char* dst = lds + (t % 3) * 49152 + 32768;
    const u16* Bbase = B + (size_t)bn * K + ((size_t)t << 6);
#pragma unroll
    for (int i = 0; i < 2; i++) {
      int D = (w * 2 + i) * 1024 + lane * 16;
      int row = D >> 7;
      int kb = (D ^ ((row & 7) << 4)) & 127;
      gload16(Bbase + (size_t)row * K + (kb >> 1), dst + D);
    }
  };

  stageA(0); stageB(0);   // 6 loads in flight

  for (int t = 0; t < NT; ++t) {
    const char* Ab = lds + (t % 3) * 49152 + wr * 8192;
    const char* Bb = lds + (t % 3) * 49152 + 32768 + wc * 8192;
    if (t + 1 < NT) {
      stageA(t + 1);
      stageB(t + 1);
      asm volatile("s_waitcnt vmcnt(6)");   // tile t complete, t+1 in flight
    } else {
      asm volatile("s_waitcnt vmcnt(0)");
    }
    asm volatile("s_barrier" ::: "memory");

    // ---- cluster 0: ksteps 0,1 ----
    bfrag8 af[2][2], bf[2][2];
#pragma unroll
    for (int ks = 0; ks < 2; ks++) {
#pragma unroll
      for (int mb = 0; mb < 2; mb++)
        af[mb][ks] = *(const bfrag8*)(Ab + mb * 4096 + (q ^ (ks << 5)));
#pragma unroll
      for (int nb = 0; nb < 2; nb++)
        bf[nb][ks] = *(const bfrag8*)(Bb + nb * 4096 + (q ^ (ks << 5)));
    }
    __builtin_amdgcn_s_setprio(1);
#pragma unroll
    for (int ks = 0; ks < 2; ks++)
#pragma unroll
      for (int mb = 0; mb < 2; mb++)
#pragma unroll
        for (int nb = 0; nb < 2; nb++)
          acc[mb][nb] = __builtin_amdgcn_mfma_f32_32x32x16_bf16(af[mb][ks], bf[nb][ks], acc[mb][nb], 0, 0, 0);
    __builtin_amdgcn_s_setprio(0);

    // ---- cluster 1: ksteps 2,3 ----
    bfrag8 af2[2][2], bf2[2][2];
#pragma unroll
    for (int ks = 0; ks < 2; ks++) {
#pragma unroll
      for (int mb = 0; mb < 2; mb++)
        af2[mb][ks] = *(const bfrag8*)(Ab + mb * 4096 + (q ^ ((ks + 2) << 5)));
#pragma unroll
      for (int nb = 0; nb < 2; nb++)
        bf2[nb][ks] = *(const bfrag8*)(Bb + nb * 4096 + (q ^ ((ks + 2) << 5)));
    }
    __builtin_amdgcn_s_setprio(1);
#pragma unroll
    for (int ks = 0; ks < 2; ks++)
#pragma unroll
      for (int mb = 0; mb < 2; mb++)
#pragma unroll
        for (int nb = 0; nb < 2; nb++)
          acc[mb][nb] = __builtin_amdgcn_mfma_f32_32x32x16_bf16(af2[mb][ks], bf2[nb][ks], acc[mb][nb], 0, 0, 0);
    __builtin_amdgcn_s_setprio(0);
  }

  // epilogue: 32x32 C layout row=(reg&3)+8*(reg>>2)+4*kg, col=r5 [m74/m101]
  const int rb0 = bm + wr * 64;
  const int cb0 = bn + wc * 64;
#pragma unroll
  for (int mb = 0; mb < 2; mb++)
#pragma unroll
    for (int nb = 0; nb < 2; nb++)
#pragma unroll
      for (int i = 0; i < 16; i++) {
        int rowl = (i & 3) + 8 * (i >> 2) + 4 * kg;
        size_t off = (size_t)(rb0 + mb * 32 + rowl) * N + cb0 + nb * 32 + r5;
        if (OUT_F32) ((float*)Cp)[off] = acc[mb][nb][i];
        else         ((u16*)Cp)[off] = f2bf(acc[mb][nb][i]);
      }
}

// ---------------- fallback bf16 NT GEMM (round-2 proven) ----------------
template<int OUT_F32>
__global__ __launch_bounds__(256) void gemm_nt(const u16* __restrict__ A,
                                               const u16* __restrict__ B,
                                               void* __restrict__ Cp,
                                               int M, int N, int K) {
  __shared__ u16 Asm[128 * 32];
  __shared__ u16 Bsm[128 * 32];
  const int tid = threadIdx.x;
  const int wv = tid >> 6, lane = tid & 63;
  const int bm = blockIdx.x * 128, bn = blockIdx.y * 128;
  const int wm = (wv >> 1) * 64, wn = (wv & 1) * 64;
  const int srow = lane >> 2;
  const int scol = (lane & 3) * 8;
  const int fr = lane & 15, fk = (lane >> 4) * 8;
  f32x4v acc[4][4];
#pragma unroll
  for (int i = 0; i < 4; i++)
#pragma unroll
    for (int j = 0; j < 4; j++) acc[i][j] = {0.f, 0.f, 0.f, 0.f};

  for (int kt = 0; kt < K; kt += 32) {
    __syncthreads();
#pragma unroll
    for (int c = 0; c < 2; c++) {
      const int ci = wv * 2 + c;
      const u16* ga = A + (size_t)(bm + ci * 16 + srow) * K + kt + scol;
      const u16* gb = B + (size_t)(bn + ci * 16 + srow) * K + kt + scol;
      gload16(ga, (char*)(Asm + ci * 512));
      gload16(gb, (char*)(Bsm + ci * 512));
    }
    __syncthreads();
    bfrag8 af[4], bf[4];
#pragma unroll
    for (int i = 0; i < 4; i++) af[i] = *(const bfrag8*)(Asm + (wm + i * 16 + fr) * 32 + fk);
#pragma unroll
    for (int j = 0; j < 4; j++) bf[j] = *(const bfrag8*)(Bsm + (wn + j * 16 + fr) * 32 + fk);
#pragma unroll
    for (int i = 0; i < 4; i++)
#pragma unroll
      for (int j = 0; j < 4; j++)
        acc[i][j] = __builtin_amdgcn_mfma_f32_16x16x32_bf16(af[i], bf[j], acc[i][j], 0, 0, 0);
  }
  const int orow = (lane >> 4) * 4, ocol = lane & 15;
#pragma unroll
  for (int i = 0; i < 4; i++)
#pragma unroll
    for (int j = 0; j < 4; j++) {
      size_t base = (size_t)(bm + wm + i * 16 + orow) * N + (size_t)(bn + wn + j * 16 + ocol);
#pragma unroll
      for (int r = 0; r < 4; r++) {
        if (OUT_F32) ((float*)Cp)[base + (size_t)r * N] = acc[i][j][r];
        else         ((u16*)Cp)[base + (size_t)r * N] = f2bf(acc[i][j][r]);
      }
    }
}

// ---------------- RoPE in-place on q,k (q also pre-scaled) ----------------
__global__ void rope_kernel(u16* __restrict__ qkv, const int* __restrict__ pos) {
  int gid = blockIdx.x * 256 + threadIdx.x;
  int d = gid & 63;
  int r = gid >> 6;
  int hh = r % 40;
  int t = r / 40;
  if (t >= T_SEQ) return;
  int off = (hh < 32) ? hh * 128 : KOFF + (hh - 32) * 128;
  u16* p = qkv + (size_t)t * QKVN + off + d;
  float x1 = bf2f(p[0]);
  float x2 = bf2f(p[64]);
  float inv_freq = exp2f(-(float)d * 0.3114307588956852f);
  float ang = (float)pos[t] * inv_freq;
  float c = cosf(ang), s = sinf(ang);
  float y1 = x1 * c - x2 * s;
  float y2 = x2 * c + x1 * s;
  if (hh < 32) { y1 *= QSCALE; y2 *= QSCALE; }
  p[0] = f2bf(y1);
  p[64] = f2bf(y2);
}

// ---------------- V transpose: qkv V region -> vt[hk][dv][t] ----------------
__global__ __launch_bounds__(256) void vt_kernel(const u16* __restrict__ qkv,
                                                 u16* __restrict__ vt) {
  __shared__ u16 tile[64][100];
  const int t0 = blockIdx.x * 64;
  const int hk = blockIdx.y;
  const int tid = threadIdx.x;
#pragma unroll
  for (int i = 0; i < 3; i++) {
    int idx = i * 256 + tid;
    int row = idx / 12, ch = idx % 12;
    const u16* g = qkv + (size_t)(t0 + row) * QKVN + VOFF + hk * DVH + ch * 8;
    uint2 a = *(const uint2*)g;
    uint2 b = *(const uint2*)(g + 4);
    *(uint2*)&tile[row][ch * 8] = a;
    *(uint2*)&tile[row][ch * 8 + 4] = b;
  }
  __syncthreads();
#pragma unroll
  for (int i = 0; i < 3; i++) {
    int idx = i * 256 + tid;
    int dv = idx >> 3, tc = (idx & 7) * 8;
    union { uint4 v4; u16 s[8]; } o;
#pragma unroll
    for (int j = 0; j < 8; j++) o.s[j] = tile[tc + j][dv];
    *(uint4*)(vt + (((size_t)(hk * 96 + dv)) << 12) + t0 + tc) = o.v4;
  }
}

// ---------------- MFMA sliding-window attention with sink ----------------
__global__ __launch_bounds__(256, 2) void attn_mfma(const u16* __restrict__ qkv,
                                                    const u16* __restrict__ vt,
                                                    const float* __restrict__ sink_bias,
                                                    u16* __restrict__ attn_out) {
  __shared__ u16 k_lds[64 * 128];
  __shared__ u16 v_lds[96 * 64];
  __shared__ u16 p_lds[4][2048];

  const int tid = threadIdx.x;
  const int wv = tid >> 6;
  const int lane = tid & 63;
  const int g = lane >> 4;
  const int c = lane & 15;
  const int t0 = blockIdx.x * 32;
  const int hk = blockIdx.y;
  const int h = hk * 4 + wv;

  bfrag8 qf[2][4];
#pragma unroll
  for (int m = 0; m < 2; m++)
#pragma unroll
    for (int kf = 0; kf < 4; kf++)
      qf[m][kf] = *(const bfrag8*)(qkv + (size_t)(t0 + m * 16 + c) * QKVN + h * DH + kf * 32 + g * 8);

  f32x4v acc_o[2][6];
#pragma unroll
  for (int m = 0; m < 2; m++)
#pragma unroll
    for (int n = 0; n < 6; n++) acc_o[m][n] = {0.f, 0.f, 0.f, 0.f};

  const float sb = sink_bias[h];
  float m_run[2][4], l_run[2][4];
#pragma unroll
  for (int m = 0; m < 2; m++)
#pragma unroll
    for (int r = 0; r < 4; r++) { m_run[m][r] = sb; l_run[m][r] = 1.0f; }

  int cb0 = t0 - (WWIN - 1);
  cb0 = (cb0 < 0) ? 0 : (cb0 & ~63);

  for (int cb = cb0; cb < t0 + 32; cb += 64) {
    __syncthreads();
#pragma unroll
    for (int it = 0; it < 4; it++) {
      int dest = it * 4096 + tid * 16;
      int row = dest >> 8;
      int src = dest ^ ((row & 7) << 4);
      const u16* gp = qkv + (size_t)(cb + row) * QKVN + KOFF + hk * DH + ((src & 255) >> 1);
      gload16(gp, (char*)k_lds + dest);
    }
#pragma unroll
    for (int it = 0; it < 3; it++) {
      int dest = it * 4096 + tid * 16;
      int row = dest >> 7;
      int src = dest ^ ((row & 7) << 4);
      const u16* gp = vt + (((size_t)(hk * 96 + row)) << 12) + cb + ((src & 127) >> 1);
      gload16(gp, (char*)v_lds + dest);
    }
    __syncthreads();

    f32x4v s[2][4];
#pragma unroll
    for (int m = 0; m < 2; m++)
#pragma unroll
      for (int n = 0; n < 4; n++) s[m][n] = {0.f, 0.f, 0.f, 0.f};
#pragma unroll
    for (int kf = 0; kf < 4; kf++) {
      bfrag8 kb[4];
#pragma unroll
      for (int n = 0; n < 4; n++) {
        int key = n * 16 + c;
        int byt = ((key << 8) + (kf << 6) + (g << 4)) ^ ((key & 7) << 4);
        kb[n] = *(const bfrag8*)((const char*)k_lds + byt);
      }
#pragma unroll
      for (int m = 0; m < 2; m++)
#pragma unroll
        for (int n = 0; n < 4; n++)
          s[m][n] = __builtin_amdgcn_mfma_f32_16x16x32_bf16(qf[m][kf], kb[n], s[m][n], 0, 0, 0);
    }

    if ((cb + 63 > t0) || (cb + WWIN < t0 + 32)) {
#pragma unroll
      for (int m = 0; m < 2; m++)
#pragma unroll
        for (int n = 0; n < 4; n++)
#pragma unroll
          for (int r = 0; r < 4; r++) {
            int rel = (t0 + m * 16 + g * 4 + r) - (cb + n * 16 + c);
            if (!(rel >= 0 && rel < WWIN)) s[m][n][r] = -3.0e38f;
          }
    }

    float corr[2][4];
#pragma unroll
    for (int m = 0; m < 2; m++)
#pragma unroll
      for (int r = 0; r < 4; r++) {
        float v0 = fmaxf(fmaxf(s[m][0][r], s[m][1][r]), fmaxf(s[m][2][r], s[m][3][r]));
        v0 = fmaxf(v0, __shfl_xor(v0, 1));
        v0 = fmaxf(v0, __shfl_xor(v0, 2));
        v0 = fmaxf(v0, __shfl_xor(v0, 4));
        v0 = fmaxf(v0, __shfl_xor(v0, 8));
        float mn = fmaxf(m_run[m][r], v0);
        corr[m][r] = __expf(m_run[m][r] - mn);
        m_run[m][r] = mn;
        float p0 = __expf(s[m][0][r] - mn);
        float p1 = __expf(s[m][1][r] - mn);
        float p2 = __expf(s[m][2][r] - mn);
        float p3 = __expf(s[m][3][r] - mn);
        s[m][0][r] = p0; s[m][1][r] = p1; s[m][2][r] = p2; s[m][3][r] = p3;
        float rs = p0 + p1 + p2 + p3;
        rs += __shfl_xor(rs, 1);
        rs += __shfl_xor(rs, 2);
        rs += __shfl_xor(rs, 4);
        rs += __shfl_xor(rs, 8);
        l_run[m][r] = l_run[m][r] * corr[m][r] + rs;
      }
#pragma unroll
    for (int m = 0; m < 2; m++)
#pragma unroll
      for (int n = 0; n < 6; n++)
#pragma unroll
      for (int r = 0; r < 4; r++) acc_o[m][n][r] *= corr[m][r];

#pragma unroll
    for (int m = 0; m < 2; m++)
#pragma unroll
      for (int n = 0; n < 4; n++) {
        u32 lo = (u32)f2bf(s[m][n][0]) | ((u32)f2bf(s[m][n][1]) << 16);
        u32 hi = (u32)f2bf(s[m][n][2]) | ((u32)f2bf(s[m][n][3]) << 16);
        int byt = ((m * 2 + (n >> 1)) << 10) | (g << 3) | ((c & 3) << 5) |
                  (((c >> 2) & 1) << 9) | ((((n & 1) * 2) + (c >> 3)) << 7);
        uint2 u; u.x = lo; u.y = hi;
        *(uint2*)((char*)&p_lds[wv][0] + byt) = u;
      }

#pragma unroll
    for (int ks = 0; ks < 2; ks++) {
      bfrag8 pa[2];
#pragma unroll
      for (int m = 0; m < 2; m++) {
        union { bfrag8 v; u16 s16[8]; } u;
#pragma unroll
        for (int j = 0; j < 4; j++) {
          int e = ((m * 2 + ks) << 9) + c + j * 16 + g * 64;
          u.s16[j] = p_lds[wv][e];
          u.s16[4 + j] = p_lds[wv][e + 256];
        }
        pa[m] = u.v;
      }
#pragma unroll
      for (int n = 0; n < 6; n++) {
        int dv = n * 16 + c;
        int byt = ((dv << 7) + (ks << 6) + (g << 4)) ^ ((dv & 7) << 4);
        bfrag8 vb = *(const bfrag8*)((const char*)v_lds + byt);
#pragma unroll
        for (int m = 0; m < 2; m++)
          acc_o[m][n] = __builtin_amdgcn_mfma_f32_16x16x32_bf16(pa[m], vb, acc_o[m][n], 0, 0, 0);
      }
    }
  }

#pragma unroll
  for (int m = 0; m < 2; m++) {
    float inv[4];
#pragma unroll
    for (int r = 0; r < 4; r++) inv[r] = 1.0f / l_run[m][r];
#pragma unroll
    for (int n = 0; n < 6; n++)
#pragma unroll
      for (int r = 0; r < 4; r++) {
        int tq = t0 + m * 16 + g * 4 + r;
        attn_out[(size_t)tq * ATTN + h * DVH + n * 16 + c] = f2bf(acc_o[m][n][r] * inv[r]);
      }
  }
}

// ---------------- launcher ----------------
extern "C" void kernel_launch(void* const* d_in, const int* in_sizes, int n_in,
                              void* d_out, int out_size, void* d_ws, size_t ws_size,
                              hipStream_t stream) {
  const int* positions = (const int*)d_in[0];
  const float* hidden = (const float*)d_in[1];
  const float* qkv_w = (const float*)d_in[2];
  const float* o_w = (const float*)d_in[3];
  const float* sink = (const float*)d_in[4];
  char* ws = (char*)d_ws;

  u16* hs_bf   = (u16*)(ws + 0);          // 16,777,216 B (dead after gemm1)
  u16* w1_bf   = (u16*)(ws + 16777216);   // 24,117,248 B (dead after gemm1)
  u16* attn_bf = (u16*)(ws + 0);          // 25,165,824 B (overlaps hs/w1)
  u16* vt_buf  = (u16*)(ws + 25165824);   //  6,291,456 B
  u16* w2_bf   = (u16*)(ws + 40894464);   // 12,582,912 B
  u16* qkv_bf  = (u16*)(ws + 53477376);   // 48,234,496 B

  bool v3Ok =
    (hipFuncSetAttribute((const void*)&gemm_v3<0>,
                         hipFuncAttributeMaxDynamicSharedMemorySize, 147456) == hipSuccess) &&
    (hipFuncSetAttribute((const void*)&gemm_v3<1>,
                         hipFuncAttributeMaxDynamicSharedMemorySize, 147456) == hipSuccess);

  cvt_kernel<<<dim3(1024), dim3(256), 0, stream>>>(hidden, hs_bf, 8388608 / 4);
  cvt_kernel<<<dim3(1024), dim3(256), 0, stream>>>(qkv_w, w1_bf, 12058624 / 4);
  cvt_kernel<<<dim3(1024), dim3(256), 0, stream>>>(o_w, w2_bf, 6291456 / 4);

  if (v3Ok)
    gemm_v3<0><<<dim3(736), dim3(512), 147456, stream>>>(hs_bf, w1_bf, (void*)qkv_bf,
                                                         T_SEQ, QKVN, HIDDEN, 16);
  else
    gemm_nt<0><<<dim3(32, 46), dim3(256), 0, stream>>>(hs_bf, w1_bf, (void*)qkv_bf,
                                                       T_SEQ, QKVN, HIDDEN);

  rope_kernel<<<dim3(40960), dim3(256), 0, stream>>>(qkv_bf, positions);
  vt_kernel<<<dim3(T_SEQ / 64, NKVH), dim3(256), 0, stream>>>(qkv_bf, vt_buf);
  attn_mfma<<<dim3(T_SEQ / 32, NKVH), dim3(256), 0, stream>>>(qkv_bf, vt_buf, sink, attn_bf);

  if (v3Ok)
    gemm_v3<1><<<dim3(256), dim3(512), 147456, stream>>>(attn_bf, w2_bf, d_out,
                                                         T_SEQ, HIDDEN, ATTN, 16);
  else
    gemm_nt<1><<<dim3(32, 16), dim3(256), 0, stream>>>(attn_bf, w2_bf, d_out,
                                                       T_SEQ, HIDDEN, ATTN);
}